// Round 4
// baseline (1658.946 us; speedup 1.0000x reference)
//
#include <hip/hip_runtime.h>
#include <math.h>

#define KTOK 30
#define HIDC 100
#define NPB  4            // nodes per block
#define SCAN_T 1024

typedef short s16x8 __attribute__((ext_vector_type(8)));
typedef float f32x4 __attribute__((ext_vector_type(4)));

// ---------------------------------------------------------------- helpers
__device__ __forceinline__ unsigned short f2bf(float f) {
    unsigned u = __float_as_uint(f);
    unsigned r = (u + 0x7FFFu + ((u >> 16) & 1u)) >> 16;
    return (unsigned short)r;
}
__device__ __forceinline__ float bf2f(unsigned short h) {
    return __uint_as_float(((unsigned)h) << 16);
}
// tanh-form GELU (max abs err ~3e-4 vs exact erf form)
__device__ __forceinline__ float gelu(float x) {
    float u = x * (1.5957691216057308f + 0.07135481627159720f * x * x);
    float e = __expf(-u);
    return x * __builtin_amdgcn_rcpf(1.0f + e);
}

// ---------------------------------------------------------------- selection pipeline
__global__ void count_kernel(const int* __restrict__ nb, int* __restrict__ cnt, int E) {
    int e = blockIdx.x * blockDim.x + threadIdx.x;
    if (e < E) atomicAdd(&cnt[nb[e]], 1);
}

__global__ void scan_kernel(const int* __restrict__ cnt, int* __restrict__ offsets, int n) {
    __shared__ int sd[SCAN_T];
    __shared__ int srun;
    if (threadIdx.x == 0) srun = 0;
    __syncthreads();
    for (int base = 0; base < n; base += SCAN_T) {
        int i = base + threadIdx.x;
        int v = (i < n) ? cnt[i] : 0;
        sd[threadIdx.x] = v;
        __syncthreads();
        for (int off = 1; off < SCAN_T; off <<= 1) {
            int tv = (threadIdx.x >= off) ? sd[threadIdx.x - off] : 0;
            __syncthreads();
            sd[threadIdx.x] += tv;
            __syncthreads();
        }
        if (i < n) offsets[i] = srun + sd[threadIdx.x] - v;
        int bsum = sd[SCAN_T - 1];
        __syncthreads();
        if (threadIdx.x == 0) srun += bsum;
        __syncthreads();
    }
}

__global__ void fill_kernel(const int* __restrict__ nb, int* __restrict__ cursor,
                            const int* __restrict__ offsets, int* __restrict__ order, int E) {
    int e = blockIdx.x * blockDim.x + threadIdx.x;
    if (e >= E) return;
    int n = nb[e];
    int p = atomicAdd(&cursor[n], 1);
    order[offsets[n] + p] = e;
}

__global__ void select_kernel(const int* __restrict__ cnt, const int* __restrict__ offsets,
                              const int* __restrict__ order, int* __restrict__ sel, int N) {
    int node = blockIdx.x * blockDim.x + threadIdx.x;
    if (node >= N) return;
    int c = cnt[node];
    int off = offsets[node];
    int top[KTOK];
    int m = 0;
    for (int i = 0; i < c; i++) {
        int e = order[off + i];
        if (m < KTOK) {
            int j = m++;
            while (j > 0 && top[j - 1] > e) { top[j] = top[j - 1]; j--; }
            top[j] = e;
        } else if (e < top[KTOK - 1]) {
            int j = KTOK - 1;
            while (j > 0 && top[j - 1] > e) { top[j] = top[j - 1]; j--; }
            top[j] = e;
        }
    }
    for (int p = 0; p < KTOK; p++) sel[node * KTOK + p] = (p < m) ? top[p] : -1;
}

// ---------------------------------------------------------------- weight fragment prep
// B-fragment layout for mfma_f32_16x16x32_bf16: lane l, elem i holds B[kt*32+(l>>4)*8+i][nt*16+(l&15)]
// Buffers (ushort elems): headWf[8][7][64][8] @0 ; wg1f[4][25][64][8] @28672 ;
//                         w2f[13][7][64][8] @79872 ; tok1f[64][8] @126464 ; tok2f[2][64][8] @126976
__global__ void prep_kernel(const float* __restrict__ head_w, const float* __restrict__ ch1_w,
                            const float* __restrict__ ch2_w, const float* __restrict__ tok1_w,
                            const float* __restrict__ tok2_w, unsigned short* __restrict__ wf) {
    int i = blockIdx.x * blockDim.x + threadIdx.x;
    if (i >= 128000) return;
    float val = 0.0f;
    if (i < 28672) {                       // headWf: B[k][n] = head_w[n][k], k<200,n<100
        int ii = i & 7, lane = (i >> 3) & 63, rest = i >> 9;
        int nt = rest % 7, kt = rest / 7;
        int k = kt * 32 + ((lane >> 4) << 3) + ii;
        int n = nt * 16 + (lane & 15);
        if (k < 200 && n < 100) val = head_w[n * 200 + k];
    } else if (i < 79872) {                // wg1f: B[k][n] = ch1_w[n][k], k<100,n<400
        int j = i - 28672;
        int ii = j & 7, lane = (j >> 3) & 63, rest = j >> 9;
        int nt = rest % 25, kt = rest / 25;
        int k = kt * 32 + ((lane >> 4) << 3) + ii;
        int n = nt * 16 + (lane & 15);
        if (k < 100) val = ch1_w[n * 100 + k];
    } else if (i < 126464) {               // w2f: B[k][n] = ch2_w[n][k], k<400,n<100
        int j = i - 79872;
        int ii = j & 7, lane = (j >> 3) & 63, rest = j >> 9;
        int nt = rest % 7, kt = rest / 7;
        int k = kt * 32 + ((lane >> 4) << 3) + ii;
        int n = nt * 16 + (lane & 15);
        if (k < 400 && n < 100) val = ch2_w[n * 400 + k];
    } else if (i < 126976) {               // tok1f: B[k][n] = tok1_w[n][k], k<30,n<15
        int j = i - 126464;
        int ii = j & 7, lane = (j >> 3) & 63;
        int k = ((lane >> 4) << 3) + ii;
        int n = lane & 15;
        if (k < 30 && n < 15) val = tok1_w[n * 30 + k];
    } else {                               // tok2f: B[k][n] = tok2_w[n][k], k<15,n<30
        int j = i - 126976;
        int ii = j & 7, lane = (j >> 3) & 63, nt = j >> 9;
        int k = ((lane >> 4) << 3) + ii;
        int n = nt * 16 + (lane & 15);
        if (k < 15 && n < 30) val = tok2_w[n * 15 + k];
    }
    wf[i] = f2bf(val);
}

// ---------------------------------------------------------------- LayerNorm over LDS rows
// 2 threads per row; stride 104 (cols 100..103 must be zero in src).
// writeMode: normalized (with g,b from GLOBAL) -> dst (stride 104, zeros cols 100..103)
// statsMode (mrsOut != null): writes m, rs to mrsOut[row*2 .. +1]
__device__ __forceinline__ void ln_pass(const unsigned short* src, unsigned short* dst,
                                        const float* __restrict__ g, const float* __restrict__ b,
                                        float* mrsOut, int t) {
    const int row = t >> 1, half = t & 1;
    const int nw = half ? 7 : 6;           // half0: cols 0..47 (6x b128), half1: 48..103 (7x b128)
    const s16x8* p = (const s16x8*)(src + row * 104 + half * 48);
    float vals[56];
    float s = 0.f, s2 = 0.f;
    #pragma unroll
    for (int q = 0; q < 7; q++) {
        if (q < nw) {
            s16x8 u = p[q];
            #pragma unroll
            for (int i2 = 0; i2 < 8; i2++) {
                float f = bf2f((unsigned short)u[i2]);
                vals[q * 8 + i2] = f;
                s += f;
                s2 = fmaf(f, f, s2);
            }
        }
    }
    s += __shfl_xor(s, 1);
    s2 += __shfl_xor(s2, 1);
    float m = s * 0.01f;
    float var = fmaxf(s2 * 0.01f - m * m, 0.f);
    float rs = rsqrtf(var + 1e-5f);
    if (mrsOut) {
        if (!half) { mrsOut[row * 2] = m; mrsOut[row * 2 + 1] = rs; }
        return;
    }
    const int c0 = half * 48;
    #pragma unroll
    for (int q = 0; q < 7; q++) {
        if (q < nw) {
            #pragma unroll
            for (int i2 = 0; i2 < 8; i2 += 2) {
                int col = c0 + q * 8 + i2;
                float f0 = (col < 100)     ? (vals[q * 8 + i2]     - m) * rs * g[col]     + b[col]     : 0.f;
                float f1 = (col + 1 < 100) ? (vals[q * 8 + i2 + 1] - m) * rs * g[col + 1] + b[col + 1] : 0.f;
                *(unsigned*)&dst[row * 104 + col] = (unsigned)f2bf(f0) | ((unsigned)f2bf(f1) << 16);
            }
        }
    }
}

// ---------------------------------------------------------------- fused per-node forward (MFMA)
// LDS plan (3 blocks/CU): xb 26624 + ab 26624 + sSel 512 + sTW 400 ~= 54272 B.
// cb (ch1-gelu chunk) ALIASES ab[0..10239] -- ab is dead there (a1f hoisted to regs);
// Phase D scratch (sMRS @ab+0, stF @byte 2048) also aliases dead ab.
__global__ __launch_bounds__(256, 3) void fused_node_kernel(
    const float* __restrict__ edge_attr, const float* __restrict__ edge_time,
    const int* __restrict__ sel, const unsigned short* __restrict__ wf,
    const float* __restrict__ head_b,
    const float* __restrict__ ln_t_g, const float* __restrict__ ln_t_b,
    const float* __restrict__ tok1_b, const float* __restrict__ tok2_b,
    const float* __restrict__ ln_c_g, const float* __restrict__ ln_c_b,
    const float* __restrict__ ch1_b, const float* __restrict__ ch2_b,
    const float* __restrict__ ln_h_g, const float* __restrict__ ln_h_b,
    const float* __restrict__ out_w, const float* __restrict__ out_b,
    float* __restrict__ out, int N) {

    __shared__ __align__(16) unsigned short xb[128 * 104];   // 26624 B: x -> h_token -> h_channel
    __shared__ __align__(16) unsigned short ab[128 * 104];   // 26624 B: IN chunks / LN out / y / cb alias / Phase-D scratch
    __shared__ int sSel[128];
    __shared__ float sTW[100];

    unsigned short* cb = ab;               // alias: ch1-gelu chunk [128][40]

    const int t = threadIdx.x;
    const int wv = t >> 6;                 // wave = node (and M-row quarter)
    const int l = t & 63;
    const s16x8 zfrag = {0, 0, 0, 0, 0, 0, 0, 0};
    const f32x4 zacc = {0.f, 0.f, 0.f, 0.f};

    const s16x8* headWf_v = (const s16x8*)(wf);
    const s16x8* wg1f_v   = (const s16x8*)(wf + 28672);
    const s16x8* w2f_v    = (const s16x8*)(wf + 79872);
    const s16x8* tok1f_v  = (const s16x8*)(wf + 126464);
    const s16x8* tok2f_v  = (const s16x8*)(wf + 126976);

    // ---- stage selection + temporal frequency table
    if (t < 128) {
        int node_g = blockIdx.x * NPB + (t >> 5);
        int tok = t & 31;
        sSel[t] = (tok < KTOK && node_g < N) ? sel[node_g * KTOK + tok] : -1;
    }
    if (t < 100) sTW[t] = exp2f(-0.33554829241286486f * (float)t);
    __syncthreads();

    // ================= Phase A: head GEMM (K chunked by 64) =================
    const int lrow = t >> 1, lhalf = t & 1;
    int le = sSel[lrow];
    const float* larow = edge_attr + (size_t)(le < 0 ? 0 : le) * 100;
    float ltime = (le >= 0) ? edge_time[le] : 0.f;

    f32x4 hacc[2][7];
    #pragma unroll
    for (int a = 0; a < 2; a++)
        #pragma unroll
        for (int c = 0; c < 7; c++) hacc[a][c] = zacc;

    for (int kc = 0; kc < 4; kc++) {
        // stage IN cols [kc*64, kc*64+64) into ab[.][0..63]
        {
            int gb = kc * 64 + lhalf * 32;
            #pragma unroll
            for (int j = 0; j < 32; j += 4) {
                float v[4];
                int gc = gb + j;
                if (gc >= 100 && gc <= 196) {
                    float4 a4 = *(const float4*)(larow + (gc - 100));
                    v[0] = a4.x; v[1] = a4.y; v[2] = a4.z; v[3] = a4.w;
                } else {
                    #pragma unroll
                    for (int q = 0; q < 4; q++) {
                        int g = gc + q;
                        v[q] = (g < 100) ? __cosf(ltime * sTW[g])
                             : (g < 200) ? larow[g - 100] : 0.f;
                    }
                }
                int lc = lhalf * 32 + j;
                *(unsigned*)&ab[lrow * 104 + lc]     = (unsigned)f2bf(v[0]) | ((unsigned)f2bf(v[1]) << 16);
                *(unsigned*)&ab[lrow * 104 + lc + 2] = (unsigned)f2bf(v[2]) | ((unsigned)f2bf(v[3]) << 16);
            }
        }
        __syncthreads();
        // MFMA: 2 ksteps x 2 mtiles x 7 ntiles
        s16x8 af[2][2];
        #pragma unroll
        for (int mt = 0; mt < 2; mt++)
            #pragma unroll
            for (int kk = 0; kk < 2; kk++)
                af[mt][kk] = *(const s16x8*)&ab[(wv * 32 + mt * 16 + (l & 15)) * 104 + kk * 32 + ((l >> 4) << 3)];
        #pragma unroll
        for (int nt = 0; nt < 7; nt++) {
            #pragma unroll
            for (int kk = 0; kk < 2; kk++) {
                s16x8 bf = headWf_v[((kc * 2 + kk) * 7 + nt) * 64 + l];
                #pragma unroll
                for (int mt = 0; mt < 2; mt++)
                    hacc[mt][nt] = __builtin_amdgcn_mfma_f32_16x16x32_bf16(af[mt][kk], bf, hacc[mt][nt], 0, 0, 0);
            }
        }
        __syncthreads();
    }
    // store x to xb (zero invalid rows; zero pad cols 100..103)
    #pragma unroll
    for (int nt = 0; nt < 7; nt++) {
        int col = nt * 16 + (l & 15);
        float bias = (col < 100) ? head_b[col] : 0.f;
        #pragma unroll
        for (int mt = 0; mt < 2; mt++) {
            #pragma unroll
            for (int jj = 0; jj < 4; jj++) {
                int row = wv * 32 + mt * 16 + ((l >> 4) << 2) + jj;
                if (col < 100)
                    xb[row * 104 + col] = (sSel[row] >= 0) ? f2bf(hacc[mt][nt][jj] + bias) : (unsigned short)0;
                else if (col < 104)
                    xb[row * 104 + col] = 0;
            }
        }
    }
    __syncthreads();

    // ================= Phase B: LN_t -> token mixer =================
    ln_pass(xb, ab, ln_t_g, ln_t_b, nullptr, t);
    __syncthreads();

    {
        // tok1: A[m=ch][k=tok] from ab; load all A-frags first (in-order DS => safe to overwrite after)
        s16x8 av[7];
        #pragma unroll
        for (int mt = 0; mt < 7; mt++) {
            int ch = mt * 16 + (l & 15);
            s16x8 a = zfrag;
            if (ch < 104) {
                #pragma unroll
                for (int i = 0; i < 8; i++) {
                    int k = ((l >> 4) << 3) + i;
                    a[i] = (short)ab[(wv * 32 + k) * 104 + ch];
                }
            }
            av[mt] = a;
        }
        s16x8 b1 = tok1f_v[l];
        float bias1 = ((l & 15) < 15) ? tok1_b[l & 15] : 0.f;
        float yv[7][4];
        #pragma unroll
        for (int mt = 0; mt < 7; mt++) {
            f32x4 y = __builtin_amdgcn_mfma_f32_16x16x32_bf16(av[mt], b1, zacc, 0, 0, 0);
            #pragma unroll
            for (int jj = 0; jj < 4; jj++) yv[mt][jj] = gelu(y[jj] + bias1);
        }
        // write y to yhome in ab: (ch,i) -> ab[wv*32 + ch/4][(ch&3)*16 + i]
        #pragma unroll
        for (int mt = 0; mt < 7; mt++) {
            #pragma unroll
            for (int jj = 0; jj < 4; jj++) {
                int ch = mt * 16 + ((l >> 4) << 2) + jj;
                ab[(wv * 32 + (ch >> 2)) * 104 + (ch & 3) * 16 + (l & 15)] = f2bf(yv[mt][jj]);
            }
        }
    }
    __syncthreads();
    {
        // tok2: A[m=ch][k=i<16] from yhome; D cols = tokens; h_token = D + tok2_b + x (RMW xb)
        s16x8 b2a = tok2f_v[l];
        s16x8 b2b = tok2f_v[64 + l];
        float tb0 = tok2_b[l & 15];
        float tb1 = ((l & 15) < 14) ? tok2_b[16 + (l & 15)] : 0.f;
        #pragma unroll
        for (int mt = 0; mt < 7; mt++) {
            int ch = mt * 16 + (l & 15);
            s16x8 a2 = zfrag;
            int gg = l >> 4;
            if (gg < 2)
                a2 = *(const s16x8*)&ab[(wv * 32 + (ch >> 2)) * 104 + (ch & 3) * 16 + gg * 8];
            f32x4 d0 = __builtin_amdgcn_mfma_f32_16x16x32_bf16(a2, b2a, zacc, 0, 0, 0);
            f32x4 d1 = __builtin_amdgcn_mfma_f32_16x16x32_bf16(a2, b2b, zacc, 0, 0, 0);
            #pragma unroll
            for (int jj = 0; jj < 4; jj++) {
                int chD = mt * 16 + ((l >> 4) << 2) + jj;
                if (chD < 100) {
                    int tok0 = l & 15;
                    int idx0 = (wv * 32 + tok0) * 104 + chD;
                    xb[idx0] = f2bf(bf2f(xb[idx0]) + d0[jj] + tb0);
                    int tok1i = 16 + (l & 15);
                    if (tok1i < 30) {
                        int idx1 = (wv * 32 + tok1i) * 104 + chD;
                        xb[idx1] = f2bf(bf2f(xb[idx1]) + d1[jj] + tb1);
                    }
                }
            }
        }
    }
    __syncthreads();

    // ================= Phase C: LN_c -> ch1 -> gelu -> ch2 (chunked) =================
    ln_pass(xb, ab, ln_c_g, ln_c_b, nullptr, t);
    __syncthreads();

    {
        // persistent A-frags of LN_c: [mt][kk]; kk=3 covers cols 96..103 (only lane-group 0)
        s16x8 a1f[2][4];
        #pragma unroll
        for (int mt = 0; mt < 2; mt++) {
            #pragma unroll
            for (int kk = 0; kk < 4; kk++) {
                s16x8 a = zfrag;
                bool ld = (kk < 3) || ((l >> 4) == 0);
                if (ld)
                    a = *(const s16x8*)&ab[(wv * 32 + mt * 16 + (l & 15)) * 104 + kk * 32 + ((l >> 4) << 3)];
                a1f[mt][kk] = a;
            }
        }
        __syncthreads();   // a1f loads complete before cb (alias of ab) is written
        f32x4 acc2[2][7];
        #pragma unroll
        for (int a = 0; a < 2; a++)
            #pragma unroll
            for (int c = 0; c < 7; c++) acc2[a][c] = zacc;

        for (int hc = 0; hc < 13; hc++) {
            f32x4 acc1[2][2];
            #pragma unroll
            for (int a = 0; a < 2; a++) { acc1[a][0] = zacc; acc1[a][1] = zacc; }
            #pragma unroll
            for (int ntl = 0; ntl < 2; ntl++) {
                int ntg = hc * 2 + ntl;
                if (ntg < 25) {
                    #pragma unroll
                    for (int kk = 0; kk < 4; kk++) {
                        s16x8 bfr = wg1f_v[(kk * 25 + ntg) * 64 + l];
                        #pragma unroll
                        for (int mt = 0; mt < 2; mt++)
                            acc1[mt][ntl] = __builtin_amdgcn_mfma_f32_16x16x32_bf16(a1f[mt][kk], bfr, acc1[mt][ntl], 0, 0, 0);
                    }
                }
            }
            // gelu -> cb chunk
            #pragma unroll
            for (int ntl = 0; ntl < 2; ntl++) {
                int ntg = hc * 2 + ntl;
                if (ntg < 25) {
                    float bias = ch1_b[ntg * 16 + (l & 15)];
                    #pragma unroll
                    for (int mt = 0; mt < 2; mt++) {
                        #pragma unroll
                        for (int jj = 0; jj < 4; jj++) {
                            int row = wv * 32 + mt * 16 + ((l >> 4) << 2) + jj;
                            cb[row * 40 + ntl * 16 + (l & 15)] = f2bf(gelu(acc1[mt][ntl][jj] + bias));
                        }
                    }
                }
            }
            __syncthreads();
            // ch2 partial: K-slice = this chunk (w2f[hc] has zeros for k>=400)
            s16x8 a2f[2];
            #pragma unroll
            for (int mt = 0; mt < 2; mt++)
                a2f[mt] = *(const s16x8*)&cb[(wv * 32 + mt * 16 + (l & 15)) * 40 + ((l >> 4) << 3)];
            #pragma unroll
            for (int nt2 = 0; nt2 < 7; nt2++) {
                s16x8 b2f = w2f_v[(hc * 7 + nt2) * 64 + l];
                #pragma unroll
                for (int mt = 0; mt < 2; mt++)
                    acc2[mt][nt2] = __builtin_amdgcn_mfma_f32_16x16x32_bf16(a2f[mt], b2f, acc2[mt][nt2], 0, 0, 0);
            }
            __syncthreads();
        }
        // h_channel = acc2 + ch2_b + h_token  -> xb
        #pragma unroll
        for (int nt2 = 0; nt2 < 7; nt2++) {
            int col = nt2 * 16 + (l & 15);
            if (col < 100) {
                float bias = ch2_b[col];
                #pragma unroll
                for (int mt = 0; mt < 2; mt++) {
                    #pragma unroll
                    for (int jj = 0; jj < 4; jj++) {
                        int row = wv * 32 + mt * 16 + ((l >> 4) << 2) + jj;
                        int idx = row * 104 + col;
                        xb[idx] = f2bf(acc2[mt][nt2][jj] + bias + bf2f(xb[idx]));
                    }
                }
            }
        }
    }
    __syncthreads();

    // ================= Phase D: LN_h stats -> mean -> out proj =================
    float* sMRS = (float*)ab;                    // 128*2 floats (bytes 0..1023 of ab)
    float* stF  = (float*)(ab + 1024);           // 400 floats (bytes 2048..3647 of ab)
    ln_pass(xb, ab, ln_h_g, ln_h_b, sMRS, t);
    __syncthreads();

    #pragma unroll
    for (int p = 0; p < 2; p++) {
        int task = p * 256 + t;
        if (task < 400) {
            int node = task / 100;
            int col = task - node * 100;
            float s = 0.f;
            for (int k = 0; k < KTOK; k++) {
                int row = node * 32 + k;
                float v = bf2f(xb[row * 104 + col]);
                s += (v - sMRS[row * 2]) * sMRS[row * 2 + 1];
            }
            stF[task] = ln_h_g[col] * s * (1.0f / 30.0f) + ln_h_b[col];
        }
    }
    __syncthreads();
    #pragma unroll
    for (int p = 0; p < 2; p++) {
        int task = p * 256 + t;
        if (task < 400) {
            int node = task / 100;
            int o = task - node * 100;
            int ng = blockIdx.x * NPB + node;
            if (ng < N) {
                float a = out_b[o];
                const float* wr = out_w + o * 100;
                const float* tv = stF + node * 100;
                #pragma unroll
                for (int c = 0; c < 100; c += 4) {
                    float4 w4 = *(const float4*)(wr + c);
                    float4 t4 = *(const float4*)(tv + c);
                    a += w4.x * t4.x + w4.y * t4.y + w4.z * t4.z + w4.w * t4.w;
                }
                out[(size_t)ng * 100 + o] = a;
            }
        }
    }
}

// ---------------------------------------------------------------- launch

extern "C" void kernel_launch(void* const* d_in, const int* in_sizes, int n_in,
                              void* d_out, int out_size, void* d_ws, size_t ws_size,
                              hipStream_t stream) {
    const float* edge_attr  = (const float*)d_in[0];
    const float* edge_time  = (const float*)d_in[1];
    const int*   node_batch = (const int*)d_in[2];
    const float* head_w = (const float*)d_in[4];
    const float* head_b = (const float*)d_in[5];
    const float* ln_t_g = (const float*)d_in[6];
    const float* ln_t_b = (const float*)d_in[7];
    const float* tok1_w = (const float*)d_in[8];
    const float* tok1_b = (const float*)d_in[9];
    const float* tok2_w = (const float*)d_in[10];
    const float* tok2_b = (const float*)d_in[11];
    const float* ln_c_g = (const float*)d_in[12];
    const float* ln_c_b = (const float*)d_in[13];
    const float* ch1_w  = (const float*)d_in[14];
    const float* ch1_b  = (const float*)d_in[15];
    const float* ch2_w  = (const float*)d_in[16];
    const float* ch2_b  = (const float*)d_in[17];
    const float* ln_h_g = (const float*)d_in[18];
    const float* ln_h_b = (const float*)d_in[19];
    const float* out_w  = (const float*)d_in[20];
    const float* out_b  = (const float*)d_in[21];
    float* out = (float*)d_out;

    const int E = in_sizes[2];
    const int N = out_size / HIDC;

    int* cnt     = (int*)d_ws;                            // N
    int* cursor  = cnt + N;                               // N
    int* offsets = cursor + N;                            // N
    int* order   = offsets + N;                           // E
    int* sel     = order + E;                             // N*K
    unsigned short* wf = (unsigned short*)(sel + (size_t)N * KTOK);  // 128000 ushort

    hipMemsetAsync(cnt, 0, (size_t)2 * N * sizeof(int), stream);
    count_kernel<<<(E + 255) / 256, 256, 0, stream>>>(node_batch, cnt, E);
    scan_kernel<<<1, SCAN_T, 0, stream>>>(cnt, offsets, N);
    fill_kernel<<<(E + 255) / 256, 256, 0, stream>>>(node_batch, cursor, offsets, order, E);
    select_kernel<<<(N + 255) / 256, 256, 0, stream>>>(cnt, offsets, order, sel, N);
    prep_kernel<<<500, 256, 0, stream>>>(head_w, ch1_w, ch2_w, tok1_w, tok2_w, wf);
    fused_node_kernel<<<(N + NPB - 1) / NPB, 256, 0, stream>>>(
        edge_attr, edge_time, sel, wf, head_b,
        ln_t_g, ln_t_b, tok1_b, tok2_b, ln_c_g, ln_c_b,
        ch1_b, ch2_b, ln_h_g, ln_h_b, out_w, out_b, out, N);
}

// Round 5
// 1482.853 us; speedup vs baseline: 1.1188x; 1.1188x over previous
//
#include <hip/hip_runtime.h>
#include <math.h>

#define KTOK 30
#define HIDC 100
#define SCAN_T 1024
#define SB() __builtin_amdgcn_sched_barrier(0)

typedef short s16x8 __attribute__((ext_vector_type(8)));
typedef float f32x4 __attribute__((ext_vector_type(4)));

// ---------------------------------------------------------------- helpers
__device__ __forceinline__ unsigned short f2bf(float f) {
    unsigned u = __float_as_uint(f);
    unsigned r = (u + 0x7FFFu + ((u >> 16) & 1u)) >> 16;
    return (unsigned short)r;
}
__device__ __forceinline__ float bf2f(unsigned short h) {
    return __uint_as_float(((unsigned)h) << 16);
}
// tanh-form GELU (max abs err ~3e-4 vs exact erf form)
__device__ __forceinline__ float gelu(float x) {
    float u = x * (1.5957691216057308f + 0.07135481627159720f * x * x);
    float e = __expf(-u);
    return x * __builtin_amdgcn_rcpf(1.0f + e);
}

// ---------------------------------------------------------------- selection pipeline
__global__ void count_kernel(const int* __restrict__ nb, int* __restrict__ cnt, int E) {
    int e = blockIdx.x * blockDim.x + threadIdx.x;
    if (e < E) atomicAdd(&cnt[nb[e]], 1);
}

__global__ void scan_kernel(const int* __restrict__ cnt, int* __restrict__ offsets, int n) {
    __shared__ int sd[SCAN_T];
    __shared__ int srun;
    if (threadIdx.x == 0) srun = 0;
    __syncthreads();
    for (int base = 0; base < n; base += SCAN_T) {
        int i = base + threadIdx.x;
        int v = (i < n) ? cnt[i] : 0;
        sd[threadIdx.x] = v;
        __syncthreads();
        for (int off = 1; off < SCAN_T; off <<= 1) {
            int tv = (threadIdx.x >= off) ? sd[threadIdx.x - off] : 0;
            __syncthreads();
            sd[threadIdx.x] += tv;
            __syncthreads();
        }
        if (i < n) offsets[i] = srun + sd[threadIdx.x] - v;
        int bsum = sd[SCAN_T - 1];
        __syncthreads();
        if (threadIdx.x == 0) srun += bsum;
        __syncthreads();
    }
}

__global__ void fill_kernel(const int* __restrict__ nb, int* __restrict__ cursor,
                            const int* __restrict__ offsets, int* __restrict__ order, int E) {
    int e = blockIdx.x * blockDim.x + threadIdx.x;
    if (e >= E) return;
    int n = nb[e];
    int p = atomicAdd(&cursor[n], 1);
    order[offsets[n] + p] = e;
}

__global__ void select_kernel(const int* __restrict__ cnt, const int* __restrict__ offsets,
                              const int* __restrict__ order, int* __restrict__ sel, int N) {
    int node = blockIdx.x * blockDim.x + threadIdx.x;
    if (node >= N) return;
    int c = cnt[node];
    int off = offsets[node];
    int top[KTOK];
    int m = 0;
    for (int i = 0; i < c; i++) {
        int e = order[off + i];
        if (m < KTOK) {
            int j = m++;
            while (j > 0 && top[j - 1] > e) { top[j] = top[j - 1]; j--; }
            top[j] = e;
        } else if (e < top[KTOK - 1]) {
            int j = KTOK - 1;
            while (j > 0 && top[j - 1] > e) { top[j] = top[j - 1]; j--; }
            top[j] = e;
        }
    }
    for (int p = 0; p < KTOK; p++) sel[node * KTOK + p] = (p < m) ? top[p] : -1;
}

// ---------------------------------------------------------------- weight fragment prep
// B-fragment layout for mfma_f32_16x16x32_bf16: lane l, elem i holds B[kt*32+(l>>4)*8+i][nt*16+(l&15)]
// Buffers (ushort elems): headWf[8][7][64][8] @0 ; wg1f[4][25][64][8] @28672 ;
//                         w2f[13][7][64][8] @79872 ; tok1f[64][8] @126464 ; tok2f[2][64][8] @126976
__global__ void prep_kernel(const float* __restrict__ head_w, const float* __restrict__ ch1_w,
                            const float* __restrict__ ch2_w, const float* __restrict__ tok1_w,
                            const float* __restrict__ tok2_w, unsigned short* __restrict__ wf) {
    int i = blockIdx.x * blockDim.x + threadIdx.x;
    if (i >= 128000) return;
    float val = 0.0f;
    if (i < 28672) {
        int ii = i & 7, lane = (i >> 3) & 63, rest = i >> 9;
        int nt = rest % 7, kt = rest / 7;
        int k = kt * 32 + ((lane >> 4) << 3) + ii;
        int n = nt * 16 + (lane & 15);
        if (k < 200 && n < 100) val = head_w[n * 200 + k];
    } else if (i < 79872) {
        int j = i - 28672;
        int ii = j & 7, lane = (j >> 3) & 63, rest = j >> 9;
        int nt = rest % 25, kt = rest / 25;
        int k = kt * 32 + ((lane >> 4) << 3) + ii;
        int n = nt * 16 + (lane & 15);
        if (k < 100) val = ch1_w[n * 100 + k];
    } else if (i < 126464) {
        int j = i - 79872;
        int ii = j & 7, lane = (j >> 3) & 63, rest = j >> 9;
        int nt = rest % 7, kt = rest / 7;
        int k = kt * 32 + ((lane >> 4) << 3) + ii;
        int n = nt * 16 + (lane & 15);
        if (k < 400 && n < 100) val = ch2_w[n * 400 + k];
    } else if (i < 126976) {
        int j = i - 126464;
        int ii = j & 7, lane = (j >> 3) & 63;
        int k = ((lane >> 4) << 3) + ii;
        int n = lane & 15;
        if (k < 30 && n < 15) val = tok1_w[n * 30 + k];
    } else {
        int j = i - 126976;
        int ii = j & 7, lane = (j >> 3) & 63, nt = j >> 9;
        int k = ((lane >> 4) << 3) + ii;
        int n = nt * 16 + (lane & 15);
        if (k < 15 && n < 30) val = tok2_w[n * 15 + k];
    }
    wf[i] = f2bf(val);
}

// ---------------------------------------------------------------- wave-local LayerNorm
// 2 lanes per row over 32 rows; src/dst stride 104 u16 (cols 100..103 zero in src).
__device__ __forceinline__ void ln_pass_w(const unsigned short* src, unsigned short* dst,
                                          const float* __restrict__ g, const float* __restrict__ b,
                                          int l) {
    const int row = l >> 1, half = l & 1;
    const int nw = half ? 7 : 6;
    const s16x8* p = (const s16x8*)(src + row * 104 + half * 48);
    float vals[56];
    float s = 0.f, s2 = 0.f;
    #pragma unroll
    for (int q = 0; q < 7; q++) {
        if (q < nw) {
            s16x8 u = p[q];
            #pragma unroll
            for (int i2 = 0; i2 < 8; i2++) {
                float f = bf2f((unsigned short)u[i2]);
                vals[q * 8 + i2] = f;
                s += f;
                s2 = fmaf(f, f, s2);
            }
        }
    }
    s += __shfl_xor(s, 1);
    s2 += __shfl_xor(s2, 1);
    float m = s * 0.01f;
    float var = fmaxf(s2 * 0.01f - m * m, 0.f);
    float rs = rsqrtf(var + 1e-5f);
    const int c0 = half * 48;
    #pragma unroll
    for (int q = 0; q < 7; q++) {
        if (q < nw) {
            #pragma unroll
            for (int i2 = 0; i2 < 8; i2 += 2) {
                int col = c0 + q * 8 + i2;
                float f0 = (col < 100)     ? (vals[q * 8 + i2]     - m) * rs * g[col]     + b[col]     : 0.f;
                float f1 = (col + 1 < 100) ? (vals[q * 8 + i2 + 1] - m) * rs * g[col + 1] + b[col + 1] : 0.f;
                *(unsigned*)&dst[row * 104 + col] = (unsigned)f2bf(f0) | ((unsigned)f2bf(f1) << 16);
            }
        }
    }
}

// ---------------------------------------------------------------- fused per-node forward (MFMA)
// 2 nodes/block, 1 wave per node, ZERO __syncthreads: all LDS traffic is wave-local
// (in-order DS pipe); sched_barrier(0) pins compile-time order at write->read handoffs.
__global__ __launch_bounds__(128, 3) void fused_node_kernel(
    const float* __restrict__ edge_attr, const float* __restrict__ edge_time,
    const int* __restrict__ sel, const unsigned short* __restrict__ wf,
    const float* __restrict__ head_b,
    const float* __restrict__ ln_t_g, const float* __restrict__ ln_t_b,
    const float* __restrict__ tok1_b, const float* __restrict__ tok2_b,
    const float* __restrict__ ln_c_g, const float* __restrict__ ln_c_b,
    const float* __restrict__ ch1_b, const float* __restrict__ ch2_b,
    const float* __restrict__ ln_h_g, const float* __restrict__ ln_h_b,
    const float* __restrict__ out_w, const float* __restrict__ out_b,
    float* __restrict__ out, int N) {

    __shared__ __align__(16) unsigned short xb2[2][32 * 104];  // x -> h_token (per wave)
    __shared__ __align__(16) unsigned short ab2[2][32 * 104];  // staging / LN out / y / cb,stF alias
    __shared__ float sTW2[2][100];
    __shared__ int   sSel2[2][32];

    const int t = threadIdx.x;
    const int wv = t >> 6, l = t & 63;
    unsigned short* xbw = xb2[wv];
    unsigned short* abw = ab2[wv];
    unsigned short* cbw = abw;                 // [32][40] u16, bytes 0..2559 (after a1f hoist)
    float* sTW  = sTW2[wv];
    int*   sSelw = sSel2[wv];
    float* stF = (float*)(abw + 2048);         // bytes 4096..4495 (dead LN_c region)
    const int node = blockIdx.x * 2 + wv;

    const s16x8 zfrag = {0, 0, 0, 0, 0, 0, 0, 0};
    const f32x4 zacc = {0.f, 0.f, 0.f, 0.f};

    const s16x8* headWf_v = (const s16x8*)(wf);
    const s16x8* wg1f_v   = (const s16x8*)(wf + 28672);
    const s16x8* w2f_v    = (const s16x8*)(wf + 79872);
    const s16x8* tok1f_v  = (const s16x8*)(wf + 126464);
    const s16x8* tok2f_v  = (const s16x8*)(wf + 126976);

    // ---- per-wave init (wave-local LDS, in-order DS => no barrier)
    if (l < 50) {
        sTW[2 * l]     = exp2f(-0.33554829241286486f * (float)(2 * l));
        sTW[2 * l + 1] = exp2f(-0.33554829241286486f * (float)(2 * l + 1));
    }
    if (l < 32) sSelw[l] = (l < KTOK && node < N) ? sel[node * KTOK + l] : -1;
    SB();

    // ================= Phase A: head GEMM (K chunked by 64) =================
    const int lrow = l >> 1, lhalf = l & 1;
    int le = sSelw[lrow];
    const float* larow = edge_attr + (size_t)(le < 0 ? 0 : le) * 100;
    float ltime = (le >= 0) ? edge_time[le] : 0.f;

    f32x4 hacc[2][7];
    #pragma unroll
    for (int a = 0; a < 2; a++)
        #pragma unroll
        for (int c = 0; c < 7; c++) hacc[a][c] = zacc;

    for (int kc = 0; kc < 4; kc++) {
        {
            int gb = kc * 64 + lhalf * 32;
            #pragma unroll
            for (int j = 0; j < 32; j += 4) {
                float v[4];
                int gc = gb + j;
                if (gc >= 100 && gc <= 196) {
                    float4 a4 = *(const float4*)(larow + (gc - 100));
                    v[0] = a4.x; v[1] = a4.y; v[2] = a4.z; v[3] = a4.w;
                } else {
                    #pragma unroll
                    for (int q = 0; q < 4; q++) {
                        int g = gc + q;
                        v[q] = (g < 100) ? __cosf(ltime * sTW[g])
                             : (g < 200) ? larow[g - 100] : 0.f;
                    }
                }
                int lc = lhalf * 32 + j;
                *(unsigned*)&abw[lrow * 104 + lc]     = (unsigned)f2bf(v[0]) | ((unsigned)f2bf(v[1]) << 16);
                *(unsigned*)&abw[lrow * 104 + lc + 2] = (unsigned)f2bf(v[2]) | ((unsigned)f2bf(v[3]) << 16);
            }
        }
        SB();
        s16x8 af[2][2];
        #pragma unroll
        for (int mt = 0; mt < 2; mt++)
            #pragma unroll
            for (int kk = 0; kk < 2; kk++)
                af[mt][kk] = *(const s16x8*)&abw[(mt * 16 + (l & 15)) * 104 + kk * 32 + ((l >> 4) << 3)];
        SB();
        #pragma unroll
        for (int nt = 0; nt < 7; nt++) {
            #pragma unroll
            for (int kk = 0; kk < 2; kk++) {
                s16x8 bf = headWf_v[((kc * 2 + kk) * 7 + nt) * 64 + l];
                #pragma unroll
                for (int mt = 0; mt < 2; mt++)
                    hacc[mt][nt] = __builtin_amdgcn_mfma_f32_16x16x32_bf16(af[mt][kk], bf, hacc[mt][nt], 0, 0, 0);
            }
        }
    }
    // store x to xbw (zero invalid rows; zero pad cols 100..103)
    #pragma unroll
    for (int nt = 0; nt < 7; nt++) {
        int col = nt * 16 + (l & 15);
        float bias = (col < 100) ? head_b[col] : 0.f;
        #pragma unroll
        for (int mt = 0; mt < 2; mt++) {
            #pragma unroll
            for (int jj = 0; jj < 4; jj++) {
                int row = mt * 16 + ((l >> 4) << 2) + jj;
                if (col < 100)
                    xbw[row * 104 + col] = (sSelw[row] >= 0) ? f2bf(hacc[mt][nt][jj] + bias) : (unsigned short)0;
                else if (col < 104)
                    xbw[row * 104 + col] = 0;
            }
        }
    }
    SB();

    // ================= Phase B: LN_t -> token mixer =================
    ln_pass_w(xbw, abw, ln_t_g, ln_t_b, l);
    SB();

    {
        s16x8 av[7];
        #pragma unroll
        for (int mt = 0; mt < 7; mt++) {
            int ch = mt * 16 + (l & 15);
            s16x8 a = zfrag;
            if (ch < 104) {
                #pragma unroll
                for (int i = 0; i < 8; i++) {
                    int k = ((l >> 4) << 3) + i;
                    a[i] = (short)abw[k * 104 + ch];
                }
            }
            av[mt] = a;
        }
        SB();
        s16x8 b1 = tok1f_v[l];
        float bias1 = ((l & 15) < 15) ? tok1_b[l & 15] : 0.f;
        float yv[7][4];
        #pragma unroll
        for (int mt = 0; mt < 7; mt++) {
            f32x4 y = __builtin_amdgcn_mfma_f32_16x16x32_bf16(av[mt], b1, zacc, 0, 0, 0);
            #pragma unroll
            for (int jj = 0; jj < 4; jj++) yv[mt][jj] = gelu(y[jj] + bias1);
        }
        // y home: (ch,i) -> abw[ch>>2][(ch&3)*16 + i]
        #pragma unroll
        for (int mt = 0; mt < 7; mt++) {
            #pragma unroll
            for (int jj = 0; jj < 4; jj++) {
                int ch = mt * 16 + ((l >> 4) << 2) + jj;
                abw[(ch >> 2) * 104 + (ch & 3) * 16 + (l & 15)] = f2bf(yv[mt][jj]);
            }
        }
    }
    SB();
    {
        s16x8 b2a = tok2f_v[l];
        s16x8 b2b = tok2f_v[64 + l];
        float tb0 = tok2_b[l & 15];
        float tb1 = ((l & 15) < 14) ? tok2_b[16 + (l & 15)] : 0.f;
        #pragma unroll
        for (int mt = 0; mt < 7; mt++) {
            int ch = mt * 16 + (l & 15);
            s16x8 a2 = zfrag;
            int gg = l >> 4;
            if (gg < 2)
                a2 = *(const s16x8*)&abw[(ch >> 2) * 104 + (ch & 3) * 16 + gg * 8];
            f32x4 d0 = __builtin_amdgcn_mfma_f32_16x16x32_bf16(a2, b2a, zacc, 0, 0, 0);
            f32x4 d1 = __builtin_amdgcn_mfma_f32_16x16x32_bf16(a2, b2b, zacc, 0, 0, 0);
            #pragma unroll
            for (int jj = 0; jj < 4; jj++) {
                int chD = mt * 16 + ((l >> 4) << 2) + jj;
                if (chD < 100) {
                    int tok0 = l & 15;
                    int idx0 = tok0 * 104 + chD;
                    xbw[idx0] = f2bf(bf2f(xbw[idx0]) + d0[jj] + tb0);
                    int tok1i = 16 + (l & 15);
                    if (tok1i < 30) {
                        int idx1 = tok1i * 104 + chD;
                        xbw[idx1] = f2bf(bf2f(xbw[idx1]) + d1[jj] + tb1);
                    }
                }
            }
        }
    }
    SB();

    // ================= Phase C: LN_c -> ch1 -> gelu -> ch2 (chunked) =================
    ln_pass_w(xbw, abw, ln_c_g, ln_c_b, l);
    SB();

    f32x4 acc2[2][7];
    {
        s16x8 a1f[2][4];
        #pragma unroll
        for (int mt = 0; mt < 2; mt++) {
            #pragma unroll
            for (int kk = 0; kk < 4; kk++) {
                s16x8 a = zfrag;
                bool ld = (kk < 3) || ((l >> 4) == 0);
                if (ld)
                    a = *(const s16x8*)&abw[(mt * 16 + (l & 15)) * 104 + kk * 32 + ((l >> 4) << 3)];
                a1f[mt][kk] = a;
            }
        }
        SB();          // a1f loaded before cbw (alias of abw) is written
        #pragma unroll
        for (int a = 0; a < 2; a++)
            #pragma unroll
            for (int c = 0; c < 7; c++) acc2[a][c] = zacc;

        for (int hc = 0; hc < 13; hc++) {
            f32x4 acc1[2][2];
            #pragma unroll
            for (int a = 0; a < 2; a++) { acc1[a][0] = zacc; acc1[a][1] = zacc; }
            #pragma unroll
            for (int ntl = 0; ntl < 2; ntl++) {
                int ntg = hc * 2 + ntl;
                if (ntg < 25) {
                    #pragma unroll
                    for (int kk = 0; kk < 4; kk++) {
                        s16x8 bfr = wg1f_v[(kk * 25 + ntg) * 64 + l];
                        #pragma unroll
                        for (int mt = 0; mt < 2; mt++)
                            acc1[mt][ntl] = __builtin_amdgcn_mfma_f32_16x16x32_bf16(a1f[mt][kk], bfr, acc1[mt][ntl], 0, 0, 0);
                    }
                }
            }
            #pragma unroll
            for (int ntl = 0; ntl < 2; ntl++) {
                int ntg = hc * 2 + ntl;
                if (ntg < 25) {
                    float bias = ch1_b[ntg * 16 + (l & 15)];
                    #pragma unroll
                    for (int mt = 0; mt < 2; mt++) {
                        #pragma unroll
                        for (int jj = 0; jj < 4; jj++) {
                            int row = mt * 16 + ((l >> 4) << 2) + jj;
                            cbw[row * 40 + ntl * 16 + (l & 15)] = f2bf(gelu(acc1[mt][ntl][jj] + bias));
                        }
                    }
                }
            }
            SB();
            s16x8 a2f[2];
            #pragma unroll
            for (int mt = 0; mt < 2; mt++)
                a2f[mt] = *(const s16x8*)&cbw[(mt * 16 + (l & 15)) * 40 + ((l >> 4) << 3)];
            SB();
            #pragma unroll
            for (int nt2 = 0; nt2 < 7; nt2++) {
                s16x8 b2f = w2f_v[(hc * 7 + nt2) * 64 + l];
                #pragma unroll
                for (int mt = 0; mt < 2; mt++)
                    acc2[mt][nt2] = __builtin_amdgcn_mfma_f32_16x16x32_bf16(a2f[mt], b2f, acc2[mt][nt2], 0, 0, 0);
            }
        }
    }

    // ================= Phase D (in registers): h_channel -> LN_h -> mean -> out proj =================
    // h_channel = acc2 + ch2_b + h_token (residual from xbw); cols>=100 stay exactly 0.
    #pragma unroll
    for (int nt = 0; nt < 7; nt++) {
        int col = nt * 16 + (l & 15);
        if (col < 100) {
            float bias = ch2_b[col];
            #pragma unroll
            for (int mt = 0; mt < 2; mt++) {
                #pragma unroll
                for (int jj = 0; jj < 4; jj++) {
                    int row = mt * 16 + ((l >> 4) << 2) + jj;
                    acc2[mt][nt][jj] += bias + bf2f(xbw[row * 104 + col]);
                }
            }
        }
    }
    // LN_h stats per row (row = mt*16 + (l>>4)*4 + jj), reduce over 16 column-lanes
    float m_[2][4], rs_[2][4];
    #pragma unroll
    for (int mt = 0; mt < 2; mt++) {
        #pragma unroll
        for (int jj = 0; jj < 4; jj++) {
            float s = 0.f, s2 = 0.f;
            #pragma unroll
            for (int nt = 0; nt < 7; nt++) {
                float v = acc2[mt][nt][jj];
                s += v;
                s2 = fmaf(v, v, s2);
            }
            #pragma unroll
            for (int msk = 1; msk < 16; msk <<= 1) {
                s  += __shfl_xor(s, msk);
                s2 += __shfl_xor(s2, msk);
            }
            float m = s * 0.01f;
            float var = fmaxf(s2 * 0.01f - m * m, 0.f);
            m_[mt][jj]  = m;
            rs_[mt][jj] = rsqrtf(var + 1e-5f);
        }
    }
    // column mean over rows<30: per-lane partial, then reduce over the 4 row-groups
    float cs[7];
    #pragma unroll
    for (int nt = 0; nt < 7; nt++) cs[nt] = 0.f;
    #pragma unroll
    for (int mt = 0; mt < 2; mt++) {
        #pragma unroll
        for (int jj = 0; jj < 4; jj++) {
            int row = mt * 16 + ((l >> 4) << 2) + jj;
            if (row < 30) {
                float m = m_[mt][jj], rs = rs_[mt][jj];
                #pragma unroll
                for (int nt = 0; nt < 7; nt++)
                    cs[nt] = fmaf(acc2[mt][nt][jj] - m, rs, cs[nt]);
            }
        }
    }
    #pragma unroll
    for (int nt = 0; nt < 7; nt++) {
        cs[nt] += __shfl_xor(cs[nt], 16);
        cs[nt] += __shfl_xor(cs[nt], 32);
    }
    if ((l >> 4) == 0) {
        #pragma unroll
        for (int nt = 0; nt < 7; nt++) {
            int col = nt * 16 + (l & 15);
            if (col < 100)
                stF[col] = ln_h_g[col] * cs[nt] * (1.0f / 30.0f) + ln_h_b[col];
        }
    }
    SB();
    // out projection: 100 outputs over 64 lanes
    #pragma unroll
    for (int p = 0; p < 2; p++) {
        int o = p * 64 + l;
        if (o < 100 && node < N) {
            float a = out_b[o];
            const float* wr = out_w + o * 100;
            #pragma unroll
            for (int c = 0; c < 100; c += 4) {
                float4 w4 = *(const float4*)(wr + c);
                f32x4 t4 = *(const f32x4*)&stF[c];
                a += w4.x * t4[0] + w4.y * t4[1] + w4.z * t4[2] + w4.w * t4[3];
            }
            out[(size_t)node * 100 + o] = a;
        }
    }
}

// ---------------------------------------------------------------- launch

extern "C" void kernel_launch(void* const* d_in, const int* in_sizes, int n_in,
                              void* d_out, int out_size, void* d_ws, size_t ws_size,
                              hipStream_t stream) {
    const float* edge_attr  = (const float*)d_in[0];
    const float* edge_time  = (const float*)d_in[1];
    const int*   node_batch = (const int*)d_in[2];
    const float* head_w = (const float*)d_in[4];
    const float* head_b = (const float*)d_in[5];
    const float* ln_t_g = (const float*)d_in[6];
    const float* ln_t_b = (const float*)d_in[7];
    const float* tok1_w = (const float*)d_in[8];
    const float* tok1_b = (const float*)d_in[9];
    const float* tok2_w = (const float*)d_in[10];
    const float* tok2_b = (const float*)d_in[11];
    const float* ln_c_g = (const float*)d_in[12];
    const float* ln_c_b = (const float*)d_in[13];
    const float* ch1_w  = (const float*)d_in[14];
    const float* ch1_b  = (const float*)d_in[15];
    const float* ch2_w  = (const float*)d_in[16];
    const float* ch2_b  = (const float*)d_in[17];
    const float* ln_h_g = (const float*)d_in[18];
    const float* ln_h_b = (const float*)d_in[19];
    const float* out_w  = (const float*)d_in[20];
    const float* out_b  = (const float*)d_in[21];
    float* out = (float*)d_out;

    const int E = in_sizes[2];
    const int N = out_size / HIDC;

    int* cnt     = (int*)d_ws;                            // N
    int* cursor  = cnt + N;                               // N
    int* offsets = cursor + N;                            // N
    int* order   = offsets + N;                           // E
    int* sel     = order + E;                             // N*K
    unsigned short* wf = (unsigned short*)(sel + (size_t)N * KTOK);  // 128000 ushort

    hipMemsetAsync(cnt, 0, (size_t)2 * N * sizeof(int), stream);
    count_kernel<<<(E + 255) / 256, 256, 0, stream>>>(node_batch, cnt, E);
    scan_kernel<<<1, SCAN_T, 0, stream>>>(cnt, offsets, N);
    fill_kernel<<<(E + 255) / 256, 256, 0, stream>>>(node_batch, cursor, offsets, order, E);
    select_kernel<<<(N + 255) / 256, 256, 0, stream>>>(cnt, offsets, order, sel, N);
    prep_kernel<<<500, 256, 0, stream>>>(head_w, ch1_w, ch2_w, tok1_w, tok2_w, wf);
    fused_node_kernel<<<(N + 1) / 2, 128, 0, stream>>>(
        edge_attr, edge_time, sel, wf, head_b,
        ln_t_g, ln_t_b, tok1_b, tok2_b, ln_c_g, ln_c_b,
        ch1_b, ch2_b, ln_h_g, ln_h_b, out_w, out_b, out, N);
}

// Round 6
// 1414.938 us; speedup vs baseline: 1.1725x; 1.0480x over previous
//
#include <hip/hip_runtime.h>
#include <math.h>

#define KTOK 30
#define HIDC 100
#define SCAN_T 1024
#define SB() __builtin_amdgcn_sched_barrier(0)

typedef short s16x8 __attribute__((ext_vector_type(8)));
typedef float f32x4 __attribute__((ext_vector_type(4)));

// ---------------------------------------------------------------- helpers
__device__ __forceinline__ unsigned short f2bf(float f) {
    unsigned u = __float_as_uint(f);
    unsigned r = (u + 0x7FFFu + ((u >> 16) & 1u)) >> 16;
    return (unsigned short)r;
}
__device__ __forceinline__ float bf2f(unsigned short h) {
    return __uint_as_float(((unsigned)h) << 16);
}
// tanh-form GELU (max abs err ~3e-4 vs exact erf form)
__device__ __forceinline__ float gelu(float x) {
    float u = x * (1.5957691216057308f + 0.07135481627159720f * x * x);
    float e = __expf(-u);
    return x * __builtin_amdgcn_rcpf(1.0f + e);
}

// ---------------------------------------------------------------- selection pipeline
__global__ void count_kernel(const int* __restrict__ nb, int* __restrict__ cnt, int E) {
    int e = blockIdx.x * blockDim.x + threadIdx.x;
    if (e < E) atomicAdd(&cnt[nb[e]], 1);
}

__global__ void scan_kernel(const int* __restrict__ cnt, int* __restrict__ offsets, int n) {
    __shared__ int sd[SCAN_T];
    __shared__ int srun;
    if (threadIdx.x == 0) srun = 0;
    __syncthreads();
    for (int base = 0; base < n; base += SCAN_T) {
        int i = base + threadIdx.x;
        int v = (i < n) ? cnt[i] : 0;
        sd[threadIdx.x] = v;
        __syncthreads();
        for (int off = 1; off < SCAN_T; off <<= 1) {
            int tv = (threadIdx.x >= off) ? sd[threadIdx.x - off] : 0;
            __syncthreads();
            sd[threadIdx.x] += tv;
            __syncthreads();
        }
        if (i < n) offsets[i] = srun + sd[threadIdx.x] - v;
        int bsum = sd[SCAN_T - 1];
        __syncthreads();
        if (threadIdx.x == 0) srun += bsum;
        __syncthreads();
    }
}

__global__ void fill_kernel(const int* __restrict__ nb, int* __restrict__ cursor,
                            const int* __restrict__ offsets, int* __restrict__ order, int E) {
    int e = blockIdx.x * blockDim.x + threadIdx.x;
    if (e >= E) return;
    int n = nb[e];
    int p = atomicAdd(&cursor[n], 1);
    order[offsets[n] + p] = e;
}

__global__ void select_kernel(const int* __restrict__ cnt, const int* __restrict__ offsets,
                              const int* __restrict__ order, int* __restrict__ sel, int N) {
    int node = blockIdx.x * blockDim.x + threadIdx.x;
    if (node >= N) return;
    int c = cnt[node];
    int off = offsets[node];
    int top[KTOK];
    int m = 0;
    for (int i = 0; i < c; i++) {
        int e = order[off + i];
        if (m < KTOK) {
            int j = m++;
            while (j > 0 && top[j - 1] > e) { top[j] = top[j - 1]; j--; }
            top[j] = e;
        } else if (e < top[KTOK - 1]) {
            int j = KTOK - 1;
            while (j > 0 && top[j - 1] > e) { top[j] = top[j - 1]; j--; }
            top[j] = e;
        }
    }
    for (int p = 0; p < KTOK; p++) sel[node * KTOK + p] = (p < m) ? top[p] : -1;
}

// ---------------------------------------------------------------- weight fragment prep
// B-fragment layout for mfma_f32_16x16x32_bf16: lane l, elem i holds B[kt*32+(l>>4)*8+i][nt*16+(l&15)]
// Buffers (ushort elems): headWf[8][7][64][8] @0 ; wg1f[4][25][64][8] @28672 ;
//                         w2f[13][7][64][8] @79872 ; tok1f[64][8] @126464 ; tok2f[2][64][8] @126976
__global__ void prep_kernel(const float* __restrict__ head_w, const float* __restrict__ ch1_w,
                            const float* __restrict__ ch2_w, const float* __restrict__ tok1_w,
                            const float* __restrict__ tok2_w, unsigned short* __restrict__ wf) {
    int i = blockIdx.x * blockDim.x + threadIdx.x;
    if (i >= 128000) return;
    float val = 0.0f;
    if (i < 28672) {
        int ii = i & 7, lane = (i >> 3) & 63, rest = i >> 9;
        int nt = rest % 7, kt = rest / 7;
        int k = kt * 32 + ((lane >> 4) << 3) + ii;
        int n = nt * 16 + (lane & 15);
        if (k < 200 && n < 100) val = head_w[n * 200 + k];
    } else if (i < 79872) {
        int j = i - 28672;
        int ii = j & 7, lane = (j >> 3) & 63, rest = j >> 9;
        int nt = rest % 25, kt = rest / 25;
        int k = kt * 32 + ((lane >> 4) << 3) + ii;
        int n = nt * 16 + (lane & 15);
        if (k < 100) val = ch1_w[n * 100 + k];
    } else if (i < 126464) {
        int j = i - 79872;
        int ii = j & 7, lane = (j >> 3) & 63, rest = j >> 9;
        int nt = rest % 7, kt = rest / 7;
        int k = kt * 32 + ((lane >> 4) << 3) + ii;
        int n = nt * 16 + (lane & 15);
        if (k < 400 && n < 100) val = ch2_w[n * 400 + k];
    } else if (i < 126976) {
        int j = i - 126464;
        int ii = j & 7, lane = (j >> 3) & 63;
        int k = ((lane >> 4) << 3) + ii;
        int n = lane & 15;
        if (k < 30 && n < 15) val = tok1_w[n * 30 + k];
    } else {
        int j = i - 126976;
        int ii = j & 7, lane = (j >> 3) & 63, nt = j >> 9;
        int k = ((lane >> 4) << 3) + ii;
        int n = nt * 16 + (lane & 15);
        if (k < 15 && n < 30) val = tok2_w[n * 15 + k];
    }
    wf[i] = f2bf(val);
}

// ---------------------------------------------------------------- wave-local LayerNorm (two-pass, low reg pressure)
// 2 lanes per row over 32 rows; src/dst stride 104 u16 (cols 100..103 zero in src).
__device__ __forceinline__ void ln_pass_w(const unsigned short* src, unsigned short* dst,
                                          const float* __restrict__ g, const float* __restrict__ b,
                                          int l) {
    const int row = l >> 1, half = l & 1;
    const int nw = half ? 7 : 6;
    const s16x8* p = (const s16x8*)(src + row * 104 + half * 48);
    // pass 1: stats only (nothing kept live)
    float s = 0.f, s2 = 0.f;
    #pragma unroll
    for (int q = 0; q < 7; q++) {
        if (q < nw) {
            s16x8 u = p[q];
            #pragma unroll
            for (int i2 = 0; i2 < 8; i2++) {
                float f = bf2f((unsigned short)u[i2]);
                s += f;
                s2 = fmaf(f, f, s2);
            }
        }
    }
    s += __shfl_xor(s, 1);
    s2 += __shfl_xor(s2, 1);
    float m = s * 0.01f;
    float var = fmaxf(s2 * 0.01f - m * m, 0.f);
    float rs = rsqrtf(var + 1e-5f);
    asm volatile("" ::: "memory");   // defeat CSE: force pass-2 re-reads (wave-local LDS, cheap)
    // pass 2: re-read, normalize, write
    const int c0 = half * 48;
    #pragma unroll
    for (int q = 0; q < 7; q++) {
        if (q < nw) {
            s16x8 u = p[q];
            #pragma unroll
            for (int i2 = 0; i2 < 8; i2 += 2) {
                int col = c0 + q * 8 + i2;
                float v0 = bf2f((unsigned short)u[i2]);
                float v1 = bf2f((unsigned short)u[i2 + 1]);
                float f0 = (col < 100)     ? (v0 - m) * rs * g[col]     + b[col]     : 0.f;
                float f1 = (col + 1 < 100) ? (v1 - m) * rs * g[col + 1] + b[col + 1] : 0.f;
                *(unsigned*)&dst[row * 104 + col] = (unsigned)f2bf(f0) | ((unsigned)f2bf(f1) << 16);
            }
        }
    }
}

// ---------------------------------------------------------------- fused per-node forward (MFMA)
// 2 nodes/block, 1 wave per node, ZERO __syncthreads (wave-local LDS, in-order DS pipe).
// LDS = 26880 B/block -> 6 blocks/CU (12 waves/CU); VGPR budget 168 (waves_per_eu=3).
__global__ __launch_bounds__(128, 3) void fused_node_kernel(
    const float* __restrict__ edge_attr, const float* __restrict__ edge_time,
    const int* __restrict__ sel, const unsigned short* __restrict__ wf,
    const float* __restrict__ head_b,
    const float* __restrict__ ln_t_g, const float* __restrict__ ln_t_b,
    const float* __restrict__ tok1_b, const float* __restrict__ tok2_b,
    const float* __restrict__ ln_c_g, const float* __restrict__ ln_c_b,
    const float* __restrict__ ch1_b, const float* __restrict__ ch2_b,
    const float* __restrict__ ln_h_g, const float* __restrict__ ln_h_b,
    const float* __restrict__ out_w, const float* __restrict__ out_b,
    float* __restrict__ out, int N) {

    __shared__ __align__(16) unsigned short xb2[2][32 * 104];  // x -> h_token (per wave)
    __shared__ __align__(16) unsigned short ab2[2][32 * 104];  // staging / LN out / y / cb,stF alias
    __shared__ int sSel2[2][32];

    const int t = threadIdx.x;
    const int wv = t >> 6, l = t & 63;
    unsigned short* xbw = xb2[wv];
    unsigned short* abw = ab2[wv];
    unsigned short* cbw = abw;                 // [32][40] u16, bytes 0..2559 (after a1f hoist)
    int*   sSelw = sSel2[wv];
    float* stF = (float*)(abw + 2048);         // bytes 4096..4495 (dead LN_c region)
    const int node = blockIdx.x * 2 + wv;

    const s16x8 zfrag = {0, 0, 0, 0, 0, 0, 0, 0};
    const f32x4 zacc = {0.f, 0.f, 0.f, 0.f};

    const s16x8* headWf_v = (const s16x8*)(wf);
    const s16x8* wg1f_v   = (const s16x8*)(wf + 28672);
    const s16x8* w2f_v    = (const s16x8*)(wf + 79872);
    const s16x8* tok1f_v  = (const s16x8*)(wf + 126464);
    const s16x8* tok2f_v  = (const s16x8*)(wf + 126976);

    // ---- per-wave init (wave-local LDS, in-order DS => no barrier)
    if (l < 32) sSelw[l] = (l < KTOK && node < N) ? sel[node * KTOK + l] : -1;
    SB();

    // ================= Phase A: head GEMM (K chunked by 64) =================
    const int lrow = l >> 1, lhalf = l & 1;
    int le = sSelw[lrow];
    const float* larow = edge_attr + (size_t)(le < 0 ? 0 : le) * 100;
    float ltime = (le >= 0) ? edge_time[le] : 0.f;

    f32x4 hacc[2][7];
    #pragma unroll
    for (int a = 0; a < 2; a++)
        #pragma unroll
        for (int c = 0; c < 7; c++) hacc[a][c] = zacc;

    for (int kc = 0; kc < 4; kc++) {
        {
            int gb = kc * 64 + lhalf * 32;
            #pragma unroll
            for (int j = 0; j < 32; j += 4) {
                float v[4];
                int gc = gb + j;
                if (gc >= 100 && gc <= 196) {
                    float4 a4 = *(const float4*)(larow + (gc - 100));
                    v[0] = a4.x; v[1] = a4.y; v[2] = a4.z; v[3] = a4.w;
                } else {
                    #pragma unroll
                    for (int q = 0; q < 4; q++) {
                        int g = gc + q;
                        v[q] = (g < 100) ? __cosf(ltime * exp2f(-0.33554829241286486f * (float)g))
                             : (g < 200) ? larow[g - 100] : 0.f;
                    }
                }
                int lc = lhalf * 32 + j;
                *(unsigned*)&abw[lrow * 104 + lc]     = (unsigned)f2bf(v[0]) | ((unsigned)f2bf(v[1]) << 16);
                *(unsigned*)&abw[lrow * 104 + lc + 2] = (unsigned)f2bf(v[2]) | ((unsigned)f2bf(v[3]) << 16);
            }
        }
        SB();
        s16x8 af[2][2];
        #pragma unroll
        for (int mt = 0; mt < 2; mt++)
            #pragma unroll
            for (int kk = 0; kk < 2; kk++)
                af[mt][kk] = *(const s16x8*)&abw[(mt * 16 + (l & 15)) * 104 + kk * 32 + ((l >> 4) << 3)];
        SB();
        #pragma unroll
        for (int nt = 0; nt < 7; nt++) {
            #pragma unroll
            for (int kk = 0; kk < 2; kk++) {
                s16x8 bf = headWf_v[((kc * 2 + kk) * 7 + nt) * 64 + l];
                #pragma unroll
                for (int mt = 0; mt < 2; mt++)
                    hacc[mt][nt] = __builtin_amdgcn_mfma_f32_16x16x32_bf16(af[mt][kk], bf, hacc[mt][nt], 0, 0, 0);
            }
        }
    }
    // store x to xbw (zero invalid rows; zero pad cols 100..103)
    #pragma unroll
    for (int nt = 0; nt < 7; nt++) {
        int col = nt * 16 + (l & 15);
        float bias = (col < 100) ? head_b[col] : 0.f;
        #pragma unroll
        for (int mt = 0; mt < 2; mt++) {
            #pragma unroll
            for (int jj = 0; jj < 4; jj++) {
                int row = mt * 16 + ((l >> 4) << 2) + jj;
                if (col < 100)
                    xbw[row * 104 + col] = (sSelw[row] >= 0) ? f2bf(hacc[mt][nt][jj] + bias) : (unsigned short)0;
                else if (col < 104)
                    xbw[row * 104 + col] = 0;
            }
        }
    }
    SB();

    // ================= Phase B: LN_t -> token mixer =================
    ln_pass_w(xbw, abw, ln_t_g, ln_t_b, l);
    SB();

    {
        s16x8 av[7];
        #pragma unroll
        for (int mt = 0; mt < 7; mt++) {
            int ch = mt * 16 + (l & 15);
            s16x8 a = zfrag;
            if (ch < 104) {
                #pragma unroll
                for (int i = 0; i < 8; i++) {
                    int k = ((l >> 4) << 3) + i;
                    a[i] = (short)abw[k * 104 + ch];
                }
            }
            av[mt] = a;
        }
        SB();
        s16x8 b1 = tok1f_v[l];
        float bias1 = ((l & 15) < 15) ? tok1_b[l & 15] : 0.f;
        float yv[7][4];
        #pragma unroll
        for (int mt = 0; mt < 7; mt++) {
            f32x4 y = __builtin_amdgcn_mfma_f32_16x16x32_bf16(av[mt], b1, zacc, 0, 0, 0);
            #pragma unroll
            for (int jj = 0; jj < 4; jj++) yv[mt][jj] = gelu(y[jj] + bias1);
        }
        // y home: (ch,i) -> abw[ch>>2][(ch&3)*16 + i]
        #pragma unroll
        for (int mt = 0; mt < 7; mt++) {
            #pragma unroll
            for (int jj = 0; jj < 4; jj++) {
                int ch = mt * 16 + ((l >> 4) << 2) + jj;
                abw[(ch >> 2) * 104 + (ch & 3) * 16 + (l & 15)] = f2bf(yv[mt][jj]);
            }
        }
    }
    SB();
    {
        s16x8 b2a = tok2f_v[l];
        s16x8 b2b = tok2f_v[64 + l];
        float tb0 = tok2_b[l & 15];
        float tb1 = ((l & 15) < 14) ? tok2_b[16 + (l & 15)] : 0.f;
        #pragma unroll
        for (int mt = 0; mt < 7; mt++) {
            int ch = mt * 16 + (l & 15);
            s16x8 a2 = zfrag;
            int gg = l >> 4;
            if (gg < 2)
                a2 = *(const s16x8*)&abw[(ch >> 2) * 104 + (ch & 3) * 16 + gg * 8];
            f32x4 d0 = __builtin_amdgcn_mfma_f32_16x16x32_bf16(a2, b2a, zacc, 0, 0, 0);
            f32x4 d1 = __builtin_amdgcn_mfma_f32_16x16x32_bf16(a2, b2b, zacc, 0, 0, 0);
            #pragma unroll
            for (int jj = 0; jj < 4; jj++) {
                int chD = mt * 16 + ((l >> 4) << 2) + jj;
                if (chD < 100) {
                    int tok0 = l & 15;
                    int idx0 = tok0 * 104 + chD;
                    xbw[idx0] = f2bf(bf2f(xbw[idx0]) + d0[jj] + tb0);
                    int tok1i = 16 + (l & 15);
                    if (tok1i < 30) {
                        int idx1 = tok1i * 104 + chD;
                        xbw[idx1] = f2bf(bf2f(xbw[idx1]) + d1[jj] + tb1);
                    }
                }
            }
        }
    }
    SB();

    // ================= Phase C: LN_c -> ch1 -> gelu -> ch2 (chunked) =================
    ln_pass_w(xbw, abw, ln_c_g, ln_c_b, l);
    SB();

    f32x4 acc2[2][7];
    {
        s16x8 a1f[2][4];
        #pragma unroll
        for (int mt = 0; mt < 2; mt++) {
            #pragma unroll
            for (int kk = 0; kk < 4; kk++) {
                s16x8 a = zfrag;
                bool ld = (kk < 3) || ((l >> 4) == 0);
                if (ld)
                    a = *(const s16x8*)&abw[(mt * 16 + (l & 15)) * 104 + kk * 32 + ((l >> 4) << 3)];
                a1f[mt][kk] = a;
            }
        }
        SB();          // a1f loaded before cbw (alias of abw) is written
        #pragma unroll
        for (int a = 0; a < 2; a++)
            #pragma unroll
            for (int c = 0; c < 7; c++) acc2[a][c] = zacc;

        for (int hc = 0; hc < 13; hc++) {
            f32x4 acc1[2][2];
            #pragma unroll
            for (int a = 0; a < 2; a++) { acc1[a][0] = zacc; acc1[a][1] = zacc; }
            #pragma unroll
            for (int ntl = 0; ntl < 2; ntl++) {
                int ntg = hc * 2 + ntl;
                if (ntg < 25) {
                    #pragma unroll
                    for (int kk = 0; kk < 4; kk++) {
                        s16x8 bfr = wg1f_v[(kk * 25 + ntg) * 64 + l];
                        #pragma unroll
                        for (int mt = 0; mt < 2; mt++)
                            acc1[mt][ntl] = __builtin_amdgcn_mfma_f32_16x16x32_bf16(a1f[mt][kk], bfr, acc1[mt][ntl], 0, 0, 0);
                    }
                }
            }
            #pragma unroll
            for (int ntl = 0; ntl < 2; ntl++) {
                int ntg = hc * 2 + ntl;
                if (ntg < 25) {
                    float bias = ch1_b[ntg * 16 + (l & 15)];
                    #pragma unroll
                    for (int mt = 0; mt < 2; mt++) {
                        #pragma unroll
                        for (int jj = 0; jj < 4; jj++) {
                            int row = mt * 16 + ((l >> 4) << 2) + jj;
                            cbw[row * 40 + ntl * 16 + (l & 15)] = f2bf(gelu(acc1[mt][ntl][jj] + bias));
                        }
                    }
                }
            }
            SB();
            s16x8 a2f[2];
            #pragma unroll
            for (int mt = 0; mt < 2; mt++)
                a2f[mt] = *(const s16x8*)&cbw[(mt * 16 + (l & 15)) * 40 + ((l >> 4) << 3)];
            SB();
            #pragma unroll
            for (int nt2 = 0; nt2 < 7; nt2++) {
                s16x8 b2f = w2f_v[(hc * 7 + nt2) * 64 + l];
                #pragma unroll
                for (int mt = 0; mt < 2; mt++)
                    acc2[mt][nt2] = __builtin_amdgcn_mfma_f32_16x16x32_bf16(a2f[mt], b2f, acc2[mt][nt2], 0, 0, 0);
            }
        }
    }

    // ================= Phase D (in registers): h_channel -> LN_h -> mean -> out proj =================
    // h_channel = acc2 + ch2_b + h_token (residual from xbw); cols>=100 stay exactly 0.
    #pragma unroll
    for (int nt = 0; nt < 7; nt++) {
        int col = nt * 16 + (l & 15);
        if (col < 100) {
            float bias = ch2_b[col];
            #pragma unroll
            for (int mt = 0; mt < 2; mt++) {
                #pragma unroll
                for (int jj = 0; jj < 4; jj++) {
                    int row = mt * 16 + ((l >> 4) << 2) + jj;
                    acc2[mt][nt][jj] += bias + bf2f(xbw[row * 104 + col]);
                }
            }
        }
    }
    // LN_h stats per row (row = mt*16 + (l>>4)*4 + jj), reduce over 16 column-lanes
    float m_[2][4], rs_[2][4];
    #pragma unroll
    for (int mt = 0; mt < 2; mt++) {
        #pragma unroll
        for (int jj = 0; jj < 4; jj++) {
            float s = 0.f, s2 = 0.f;
            #pragma unroll
            for (int nt = 0; nt < 7; nt++) {
                float v = acc2[mt][nt][jj];
                s += v;
                s2 = fmaf(v, v, s2);
            }
            #pragma unroll
            for (int msk = 1; msk < 16; msk <<= 1) {
                s  += __shfl_xor(s, msk);
                s2 += __shfl_xor(s2, msk);
            }
            float m = s * 0.01f;
            float var = fmaxf(s2 * 0.01f - m * m, 0.f);
            m_[mt][jj]  = m;
            rs_[mt][jj] = rsqrtf(var + 1e-5f);
        }
    }
    // column mean over rows<30: per-lane partial, then reduce over the 4 row-groups
    float cs[7];
    #pragma unroll
    for (int nt = 0; nt < 7; nt++) cs[nt] = 0.f;
    #pragma unroll
    for (int mt = 0; mt < 2; mt++) {
        #pragma unroll
        for (int jj = 0; jj < 4; jj++) {
            int row = mt * 16 + ((l >> 4) << 2) + jj;
            if (row < 30) {
                float m = m_[mt][jj], rs = rs_[mt][jj];
                #pragma unroll
                for (int nt = 0; nt < 7; nt++)
                    cs[nt] = fmaf(acc2[mt][nt][jj] - m, rs, cs[nt]);
            }
        }
    }
    #pragma unroll
    for (int nt = 0; nt < 7; nt++) {
        cs[nt] += __shfl_xor(cs[nt], 16);
        cs[nt] += __shfl_xor(cs[nt], 32);
    }
    if ((l >> 4) == 0) {
        #pragma unroll
        for (int nt = 0; nt < 7; nt++) {
            int col = nt * 16 + (l & 15);
            if (col < 100)
                stF[col] = ln_h_g[col] * cs[nt] * (1.0f / 30.0f) + ln_h_b[col];
        }
    }
    SB();
    // out projection: 100 outputs over 64 lanes
    #pragma unroll
    for (int p = 0; p < 2; p++) {
        int o = p * 64 + l;
        if (o < 100 && node < N) {
            float a = out_b[o];
            const float* wr = out_w + o * 100;
            #pragma unroll
            for (int c = 0; c < 100; c += 4) {
                float4 w4 = *(const float4*)(wr + c);
                f32x4 t4 = *(const f32x4*)&stF[c];
                a += w4.x * t4[0] + w4.y * t4[1] + w4.z * t4[2] + w4.w * t4[3];
            }
            out[(size_t)node * 100 + o] = a;
        }
    }
}

// ---------------------------------------------------------------- launch

extern "C" void kernel_launch(void* const* d_in, const int* in_sizes, int n_in,
                              void* d_out, int out_size, void* d_ws, size_t ws_size,
                              hipStream_t stream) {
    const float* edge_attr  = (const float*)d_in[0];
    const float* edge_time  = (const float*)d_in[1];
    const int*   node_batch = (const int*)d_in[2];
    const float* head_w = (const float*)d_in[4];
    const float* head_b = (const float*)d_in[5];
    const float* ln_t_g = (const float*)d_in[6];
    const float* ln_t_b = (const float*)d_in[7];
    const float* tok1_w = (const float*)d_in[8];
    const float* tok1_b = (const float*)d_in[9];
    const float* tok2_w = (const float*)d_in[10];
    const float* tok2_b = (const float*)d_in[11];
    const float* ln_c_g = (const float*)d_in[12];
    const float* ln_c_b = (const float*)d_in[13];
    const float* ch1_w  = (const float*)d_in[14];
    const float* ch1_b  = (const float*)d_in[15];
    const float* ch2_w  = (const float*)d_in[16];
    const float* ch2_b  = (const float*)d_in[17];
    const float* ln_h_g = (const float*)d_in[18];
    const float* ln_h_b = (const float*)d_in[19];
    const float* out_w  = (const float*)d_in[20];
    const float* out_b  = (const float*)d_in[21];
    float* out = (float*)d_out;

    const int E = in_sizes[2];
    const int N = out_size / HIDC;

    int* cnt     = (int*)d_ws;                            // N
    int* cursor  = cnt + N;                               // N
    int* offsets = cursor + N;                            // N
    int* order   = offsets + N;                           // E
    int* sel     = order + E;                             // N*K
    unsigned short* wf = (unsigned short*)(sel + (size_t)N * KTOK);  // 128000 ushort

    hipMemsetAsync(cnt, 0, (size_t)2 * N * sizeof(int), stream);
    count_kernel<<<(E + 255) / 256, 256, 0, stream>>>(node_batch, cnt, E);
    scan_kernel<<<1, SCAN_T, 0, stream>>>(cnt, offsets, N);
    fill_kernel<<<(E + 255) / 256, 256, 0, stream>>>(node_batch, cursor, offsets, order, E);
    select_kernel<<<(N + 255) / 256, 256, 0, stream>>>(cnt, offsets, order, sel, N);
    prep_kernel<<<500, 256, 0, stream>>>(head_w, ch1_w, ch2_w, tok1_w, tok2_w, wf);
    fused_node_kernel<<<(N + 1) / 2, 128, 0, stream>>>(
        edge_attr, edge_time, sel, wf, head_b,
        ln_t_g, ln_t_b, tok1_b, tok2_b, ln_c_g, ln_c_b,
        ch1_b, ch2_b, ln_h_g, ln_h_b, out_w, out_b, out, N);
}

// Round 7
// 1337.976 us; speedup vs baseline: 1.2399x; 1.0575x over previous
//
#include <hip/hip_runtime.h>
#include <math.h>

#define KTOK 30
#define HIDC 100
#define SCAN_T 1024
#define SB() __builtin_amdgcn_sched_barrier(0)

typedef short s16x8 __attribute__((ext_vector_type(8)));
typedef float f32x4 __attribute__((ext_vector_type(4)));

// ---------------------------------------------------------------- helpers
// HW packed f32->bf16 (RNE), 1 VALU op for a pair (or a single in the low half)
__device__ __forceinline__ unsigned cvt_pk_bf16(float lo, float hi) {
    unsigned r;
    asm("v_cvt_pk_bf16_f32 %0, %1, %2" : "=v"(r) : "v"(lo), "v"(hi));
    return r;
}
__device__ __forceinline__ unsigned short cvt_bf16(float x) {
    unsigned r;
    asm("v_cvt_pk_bf16_f32 %0, %1, 0" : "=v"(r) : "v"(x));
    return (unsigned short)r;
}
__device__ __forceinline__ float bf2f(unsigned short h) {
    return __uint_as_float(((unsigned)h) << 16);
}
__device__ __forceinline__ float exp2_fast(float x) {
    float r;
    asm("v_exp_f32 %0, %1" : "=v"(r) : "v"(x));
    return r;
}
// cos with input in REVOLUTIONS; valid here since |rev| <= 1/(2pi) < 1
__device__ __forceinline__ float cos_rev(float rev) {
    float r;
    asm("v_cos_f32 %0, %1" : "=v"(r) : "v"(rev));
    return r;
}
// software f2bf (host-prep kernel only paths keep exact old behavior)
__device__ __forceinline__ unsigned short f2bf(float f) {
    unsigned u = __float_as_uint(f);
    unsigned r = (u + 0x7FFFu + ((u >> 16) & 1u)) >> 16;
    return (unsigned short)r;
}
// tanh-form GELU, log2e folded into polynomial: gelu(x) = x / (1 + 2^(-x*(c1+c2*x^2)))
__device__ __forceinline__ float gelu(float x) {
    float s = x * x;
    float t = fmaf(s, 0.10294334f, 2.3022082f);
    float e = exp2_fast(-x * t);
    return x * __builtin_amdgcn_rcpf(1.0f + e);
}

// ---------------------------------------------------------------- selection pipeline
__global__ void count_kernel(const int* __restrict__ nb, int* __restrict__ cnt, int E) {
    int e = blockIdx.x * blockDim.x + threadIdx.x;
    if (e < E) atomicAdd(&cnt[nb[e]], 1);
}

__global__ void scan_kernel(const int* __restrict__ cnt, int* __restrict__ offsets, int n) {
    __shared__ int sd[SCAN_T];
    __shared__ int srun;
    if (threadIdx.x == 0) srun = 0;
    __syncthreads();
    for (int base = 0; base < n; base += SCAN_T) {
        int i = base + threadIdx.x;
        int v = (i < n) ? cnt[i] : 0;
        sd[threadIdx.x] = v;
        __syncthreads();
        for (int off = 1; off < SCAN_T; off <<= 1) {
            int tv = (threadIdx.x >= off) ? sd[threadIdx.x - off] : 0;
            __syncthreads();
            sd[threadIdx.x] += tv;
            __syncthreads();
        }
        if (i < n) offsets[i] = srun + sd[threadIdx.x] - v;
        int bsum = sd[SCAN_T - 1];
        __syncthreads();
        if (threadIdx.x == 0) srun += bsum;
        __syncthreads();
    }
}

__global__ void fill_kernel(const int* __restrict__ nb, int* __restrict__ cursor,
                            const int* __restrict__ offsets, int* __restrict__ order, int E) {
    int e = blockIdx.x * blockDim.x + threadIdx.x;
    if (e >= E) return;
    int n = nb[e];
    int p = atomicAdd(&cursor[n], 1);
    order[offsets[n] + p] = e;
}

__global__ void select_kernel(const int* __restrict__ cnt, const int* __restrict__ offsets,
                              const int* __restrict__ order, int* __restrict__ sel, int N) {
    int node = blockIdx.x * blockDim.x + threadIdx.x;
    if (node >= N) return;
    int c = cnt[node];
    int off = offsets[node];
    int top[KTOK];
    int m = 0;
    for (int i = 0; i < c; i++) {
        int e = order[off + i];
        if (m < KTOK) {
            int j = m++;
            while (j > 0 && top[j - 1] > e) { top[j] = top[j - 1]; j--; }
            top[j] = e;
        } else if (e < top[KTOK - 1]) {
            int j = KTOK - 1;
            while (j > 0 && top[j - 1] > e) { top[j] = top[j - 1]; j--; }
            top[j] = e;
        }
    }
    for (int p = 0; p < KTOK; p++) sel[node * KTOK + p] = (p < m) ? top[p] : -1;
}

// ---------------------------------------------------------------- weight fragment prep
// B-fragment layout for mfma_f32_16x16x32_bf16: lane l, elem i holds B[kt*32+(l>>4)*8+i][nt*16+(l&15)]
// Buffers (ushort elems): headWf[8][7][64][8] @0 ; wg1f[4][25][64][8] @28672 ;
//                         w2f[13][7][64][8] @79872 ; tok1f[64][8] @126464 ; tok2f[2][64][8] @126976
__global__ void prep_kernel(const float* __restrict__ head_w, const float* __restrict__ ch1_w,
                            const float* __restrict__ ch2_w, const float* __restrict__ tok1_w,
                            const float* __restrict__ tok2_w, unsigned short* __restrict__ wf) {
    int i = blockIdx.x * blockDim.x + threadIdx.x;
    if (i >= 128000) return;
    float val = 0.0f;
    if (i < 28672) {
        int ii = i & 7, lane = (i >> 3) & 63, rest = i >> 9;
        int nt = rest % 7, kt = rest / 7;
        int k = kt * 32 + ((lane >> 4) << 3) + ii;
        int n = nt * 16 + (lane & 15);
        if (k < 200 && n < 100) val = head_w[n * 200 + k];
    } else if (i < 79872) {
        int j = i - 28672;
        int ii = j & 7, lane = (j >> 3) & 63, rest = j >> 9;
        int nt = rest % 25, kt = rest / 25;
        int k = kt * 32 + ((lane >> 4) << 3) + ii;
        int n = nt * 16 + (lane & 15);
        if (k < 100) val = ch1_w[n * 100 + k];
    } else if (i < 126464) {
        int j = i - 79872;
        int ii = j & 7, lane = (j >> 3) & 63, rest = j >> 9;
        int nt = rest % 7, kt = rest / 7;
        int k = kt * 32 + ((lane >> 4) << 3) + ii;
        int n = nt * 16 + (lane & 15);
        if (k < 400 && n < 100) val = ch2_w[n * 400 + k];
    } else if (i < 126976) {
        int j = i - 126464;
        int ii = j & 7, lane = (j >> 3) & 63;
        int k = ((lane >> 4) << 3) + ii;
        int n = lane & 15;
        if (k < 30 && n < 15) val = tok1_w[n * 30 + k];
    } else {
        int j = i - 126976;
        int ii = j & 7, lane = (j >> 3) & 63, nt = j >> 9;
        int k = ((lane >> 4) << 3) + ii;
        int n = nt * 16 + (lane & 15);
        if (k < 15 && n < 30) val = tok2_w[n * 15 + k];
    }
    wf[i] = f2bf(val);
}

// ---------------------------------------------------------------- wave-local LayerNorm (two-pass, low reg pressure)
// 2 lanes per row over 32 rows; src/dst stride 104 u16 (cols 100..103 zero in src).
__device__ __forceinline__ void ln_pass_w(const unsigned short* src, unsigned short* dst,
                                          const float* __restrict__ g, const float* __restrict__ b,
                                          int l) {
    const int row = l >> 1, half = l & 1;
    const int nw = half ? 7 : 6;
    const s16x8* p = (const s16x8*)(src + row * 104 + half * 48);
    // pass 1: stats only (nothing kept live)
    float s = 0.f, s2 = 0.f;
    #pragma unroll
    for (int q = 0; q < 7; q++) {
        if (q < nw) {
            s16x8 u = p[q];
            #pragma unroll
            for (int i2 = 0; i2 < 8; i2++) {
                float f = bf2f((unsigned short)u[i2]);
                s += f;
                s2 = fmaf(f, f, s2);
            }
        }
    }
    s += __shfl_xor(s, 1);
    s2 += __shfl_xor(s2, 1);
    float m = s * 0.01f;
    float var = fmaxf(s2 * 0.01f - m * m, 0.f);
    float rs = rsqrtf(var + 1e-5f);
    asm volatile("" ::: "memory");   // defeat CSE: force pass-2 re-reads (wave-local LDS, cheap)
    // pass 2: re-read, normalize, write (packed convert)
    const int c0 = half * 48;
    #pragma unroll
    for (int q = 0; q < 7; q++) {
        if (q < nw) {
            s16x8 u = p[q];
            #pragma unroll
            for (int i2 = 0; i2 < 8; i2 += 2) {
                int col = c0 + q * 8 + i2;
                float v0 = bf2f((unsigned short)u[i2]);
                float v1 = bf2f((unsigned short)u[i2 + 1]);
                float f0 = (col < 100)     ? (v0 - m) * rs * g[col]     + b[col]     : 0.f;
                float f1 = (col + 1 < 100) ? (v1 - m) * rs * g[col + 1] + b[col + 1] : 0.f;
                *(unsigned*)&dst[row * 104 + col] = cvt_pk_bf16(f0, f1);
            }
        }
    }
}

// ---------------------------------------------------------------- fused per-node forward (MFMA)
// 2 nodes/block, 1 wave per node, ZERO __syncthreads (wave-local LDS, in-order DS pipe).
// LDS ~27 KB/block -> 6 blocks/CU (12 waves/CU); VGPR budget 168 (waves_per_eu=3).
__global__ __launch_bounds__(128, 3) void fused_node_kernel(
    const float* __restrict__ edge_attr, const float* __restrict__ edge_time,
    const int* __restrict__ sel, const unsigned short* __restrict__ wf,
    const float* __restrict__ head_b,
    const float* __restrict__ ln_t_g, const float* __restrict__ ln_t_b,
    const float* __restrict__ tok1_b, const float* __restrict__ tok2_b,
    const float* __restrict__ ln_c_g, const float* __restrict__ ln_c_b,
    const float* __restrict__ ch1_b, const float* __restrict__ ch2_b,
    const float* __restrict__ ln_h_g, const float* __restrict__ ln_h_b,
    const float* __restrict__ out_w, const float* __restrict__ out_b,
    float* __restrict__ out, int N) {

    __shared__ __align__(16) unsigned short xb2[2][32 * 104];  // x -> h_token (per wave)
    __shared__ __align__(16) unsigned short ab2[2][32 * 104];  // staging / LN out / y / cb,stF alias
    __shared__ int sSel2[2][32];

    const int t = threadIdx.x;
    const int wv = t >> 6, l = t & 63;
    unsigned short* xbw = xb2[wv];
    unsigned short* abw = ab2[wv];
    unsigned short* cbw = abw;                 // [32][40] u16, bytes 0..2559 (after a1f hoist)
    int*   sSelw = sSel2[wv];
    float* stF = (float*)(abw + 2048);         // bytes 4096..4495 (dead LN_c region)
    const int node = blockIdx.x * 2 + wv;

    const s16x8 zfrag = {0, 0, 0, 0, 0, 0, 0, 0};
    const f32x4 zacc = {0.f, 0.f, 0.f, 0.f};

    const s16x8* headWf_v = (const s16x8*)(wf);
    const s16x8* wg1f_v   = (const s16x8*)(wf + 28672);
    const s16x8* w2f_v    = (const s16x8*)(wf + 79872);
    const s16x8* tok1f_v  = (const s16x8*)(wf + 126464);
    const s16x8* tok2f_v  = (const s16x8*)(wf + 126976);

    // ---- per-wave init (wave-local LDS, in-order DS => no barrier)
    if (l < 32) sSelw[l] = (l < KTOK && node < N) ? sel[node * KTOK + l] : -1;
    SB();

    // ================= Phase A: head GEMM (K chunked by 64) =================
    const int lrow = l >> 1, lhalf = l & 1;
    int le = sSelw[lrow];
    const float* larow = edge_attr + (size_t)(le < 0 ? 0 : le) * 100;
    float ltime = (le >= 0) ? edge_time[le] : 0.f;
    // temporal: IN[c] = cos(t * rho^c), rho = 2^-0.33554829; in revolutions:
    // rev(c) = (t/2pi) * rho^c, rev <= 1/(2pi) < 1 -> v_cos directly.
    const float Trev = ltime * 0.15915494309189535f;

    f32x4 hacc[2][7];
    #pragma unroll
    for (int a = 0; a < 2; a++)
        #pragma unroll
        for (int c = 0; c < 7; c++) hacc[a][c] = zacc;

    #pragma unroll
    for (int kc = 0; kc < 4; kc++) {
        {
            const int gb = kc * 64 + lhalf * 32;
            const float A = Trev * exp2_fast(-0.33554829241286486f * (float)gb);
            #pragma unroll
            for (int j = 0; j < 32; j += 4) {
                float v[4];
                int gc = gb + j;
                if (gc >= 100 && gc <= 196) {
                    float4 a4 = *(const float4*)(larow + (gc - 100));
                    v[0] = a4.x; v[1] = a4.y; v[2] = a4.z; v[3] = a4.w;
                } else {
                    #pragma unroll
                    for (int q = 0; q < 4; q++) {
                        int g = gc + q;
                        // rho^(j+q) folds to a literal (j,q compile-time)
                        v[q] = (g < 100) ? cos_rev(A * exp2f(-0.33554829241286486f * (float)(j + q)))
                             : (g < 200) ? larow[g - 100] : 0.f;
                    }
                }
                int lc = lhalf * 32 + j;
                *(unsigned*)&abw[lrow * 104 + lc]     = cvt_pk_bf16(v[0], v[1]);
                *(unsigned*)&abw[lrow * 104 + lc + 2] = cvt_pk_bf16(v[2], v[3]);
            }
        }
        SB();
        s16x8 af[2][2];
        #pragma unroll
        for (int mt = 0; mt < 2; mt++)
            #pragma unroll
            for (int kk = 0; kk < 2; kk++)
                af[mt][kk] = *(const s16x8*)&abw[(mt * 16 + (l & 15)) * 104 + kk * 32 + ((l >> 4) << 3)];
        SB();
        #pragma unroll
        for (int nt = 0; nt < 7; nt++) {
            #pragma unroll
            for (int kk = 0; kk < 2; kk++) {
                s16x8 bf = headWf_v[((kc * 2 + kk) * 7 + nt) * 64 + l];
                #pragma unroll
                for (int mt = 0; mt < 2; mt++)
                    hacc[mt][nt] = __builtin_amdgcn_mfma_f32_16x16x32_bf16(af[mt][kk], bf, hacc[mt][nt], 0, 0, 0);
            }
        }
    }
    // store x to xbw (zero invalid rows; zero pad cols 100..103)
    #pragma unroll
    for (int nt = 0; nt < 7; nt++) {
        int col = nt * 16 + (l & 15);
        float bias = (col < 100) ? head_b[col] : 0.f;
        #pragma unroll
        for (int mt = 0; mt < 2; mt++) {
            #pragma unroll
            for (int jj = 0; jj < 4; jj++) {
                int row = mt * 16 + ((l >> 4) << 2) + jj;
                if (col < 100)
                    xbw[row * 104 + col] = (sSelw[row] >= 0) ? cvt_bf16(hacc[mt][nt][jj] + bias) : (unsigned short)0;
                else if (col < 104)
                    xbw[row * 104 + col] = 0;
            }
        }
    }
    SB();

    // ================= Phase B: LN_t -> token mixer =================
    ln_pass_w(xbw, abw, ln_t_g, ln_t_b, l);
    SB();

    {
        s16x8 av[7];
        #pragma unroll
        for (int mt = 0; mt < 7; mt++) {
            int ch = mt * 16 + (l & 15);
            s16x8 a = zfrag;
            if (ch < 104) {
                #pragma unroll
                for (int i = 0; i < 8; i++) {
                    int k = ((l >> 4) << 3) + i;
                    a[i] = (short)abw[k * 104 + ch];
                }
            }
            av[mt] = a;
        }
        SB();
        s16x8 b1 = tok1f_v[l];
        float bias1 = ((l & 15) < 15) ? tok1_b[l & 15] : 0.f;
        // MFMA -> gelu -> write per mt (keeps liveness at 4 floats, av already in regs)
        #pragma unroll
        for (int mt = 0; mt < 7; mt++) {
            f32x4 y = __builtin_amdgcn_mfma_f32_16x16x32_bf16(av[mt], b1, zacc, 0, 0, 0);
            #pragma unroll
            for (int jj = 0; jj < 4; jj++) {
                int ch = mt * 16 + ((l >> 4) << 2) + jj;
                abw[(ch >> 2) * 104 + (ch & 3) * 16 + (l & 15)] = cvt_bf16(gelu(y[jj] + bias1));
            }
        }
    }
    SB();
    {
        s16x8 b2a = tok2f_v[l];
        s16x8 b2b = tok2f_v[64 + l];
        float tb0 = tok2_b[l & 15];
        float tb1 = ((l & 15) < 14) ? tok2_b[16 + (l & 15)] : 0.f;
        #pragma unroll
        for (int mt = 0; mt < 7; mt++) {
            int ch = mt * 16 + (l & 15);
            s16x8 a2 = zfrag;
            int gg = l >> 4;
            if (gg < 2)
                a2 = *(const s16x8*)&abw[(ch >> 2) * 104 + (ch & 3) * 16 + gg * 8];
            f32x4 d0 = __builtin_amdgcn_mfma_f32_16x16x32_bf16(a2, b2a, zacc, 0, 0, 0);
            f32x4 d1 = __builtin_amdgcn_mfma_f32_16x16x32_bf16(a2, b2b, zacc, 0, 0, 0);
            #pragma unroll
            for (int jj = 0; jj < 4; jj++) {
                int chD = mt * 16 + ((l >> 4) << 2) + jj;
                if (chD < 100) {
                    int tok0 = l & 15;
                    int idx0 = tok0 * 104 + chD;
                    xbw[idx0] = cvt_bf16(bf2f(xbw[idx0]) + d0[jj] + tb0);
                    int tok1i = 16 + (l & 15);
                    if (tok1i < 30) {
                        int idx1 = tok1i * 104 + chD;
                        xbw[idx1] = cvt_bf16(bf2f(xbw[idx1]) + d1[jj] + tb1);
                    }
                }
            }
        }
    }
    SB();

    // ================= Phase C: LN_c -> ch1 -> gelu -> ch2 (chunked) =================
    ln_pass_w(xbw, abw, ln_c_g, ln_c_b, l);
    SB();

    f32x4 acc2[2][7];
    {
        s16x8 a1f[2][4];
        #pragma unroll
        for (int mt = 0; mt < 2; mt++) {
            #pragma unroll
            for (int kk = 0; kk < 4; kk++) {
                s16x8 a = zfrag;
                bool ld = (kk < 3) || ((l >> 4) == 0);
                if (ld)
                    a = *(const s16x8*)&abw[(mt * 16 + (l & 15)) * 104 + kk * 32 + ((l >> 4) << 3)];
                a1f[mt][kk] = a;
            }
        }
        SB();          // a1f loaded before cbw (alias of abw) is written
        #pragma unroll
        for (int a = 0; a < 2; a++)
            #pragma unroll
            for (int c = 0; c < 7; c++) acc2[a][c] = zacc;

        for (int hc = 0; hc < 13; hc++) {
            f32x4 acc1[2][2];
            #pragma unroll
            for (int a = 0; a < 2; a++) { acc1[a][0] = zacc; acc1[a][1] = zacc; }
            #pragma unroll
            for (int ntl = 0; ntl < 2; ntl++) {
                int ntg = hc * 2 + ntl;
                if (ntg < 25) {
                    #pragma unroll
                    for (int kk = 0; kk < 4; kk++) {
                        s16x8 bfr = wg1f_v[(kk * 25 + ntg) * 64 + l];
                        #pragma unroll
                        for (int mt = 0; mt < 2; mt++)
                            acc1[mt][ntl] = __builtin_amdgcn_mfma_f32_16x16x32_bf16(a1f[mt][kk], bfr, acc1[mt][ntl], 0, 0, 0);
                    }
                }
            }
            #pragma unroll
            for (int ntl = 0; ntl < 2; ntl++) {
                int ntg = hc * 2 + ntl;
                if (ntg < 25) {
                    float bias = ch1_b[ntg * 16 + (l & 15)];
                    #pragma unroll
                    for (int mt = 0; mt < 2; mt++) {
                        #pragma unroll
                        for (int jj = 0; jj < 4; jj++) {
                            int row = mt * 16 + ((l >> 4) << 2) + jj;
                            cbw[row * 40 + ntl * 16 + (l & 15)] = cvt_bf16(gelu(acc1[mt][ntl][jj] + bias));
                        }
                    }
                }
            }
            SB();
            s16x8 a2f[2];
            #pragma unroll
            for (int mt = 0; mt < 2; mt++)
                a2f[mt] = *(const s16x8*)&cbw[(mt * 16 + (l & 15)) * 40 + ((l >> 4) << 3)];
            SB();
            #pragma unroll
            for (int nt2 = 0; nt2 < 7; nt2++) {
                s16x8 b2f = w2f_v[(hc * 7 + nt2) * 64 + l];
                #pragma unroll
                for (int mt = 0; mt < 2; mt++)
                    acc2[mt][nt2] = __builtin_amdgcn_mfma_f32_16x16x32_bf16(a2f[mt], b2f, acc2[mt][nt2], 0, 0, 0);
            }
        }
    }

    // ================= Phase D (in registers): h_channel -> LN_h -> mean -> out proj =================
    // h_channel = acc2 + ch2_b + h_token (residual from xbw); cols>=100 stay exactly 0.
    #pragma unroll
    for (int nt = 0; nt < 7; nt++) {
        int col = nt * 16 + (l & 15);
        if (col < 100) {
            float bias = ch2_b[col];
            #pragma unroll
            for (int mt = 0; mt < 2; mt++) {
                #pragma unroll
                for (int jj = 0; jj < 4; jj++) {
                    int row = mt * 16 + ((l >> 4) << 2) + jj;
                    acc2[mt][nt][jj] += bias + bf2f(xbw[row * 104 + col]);
                }
            }
        }
    }
    // LN_h stats per row (row = mt*16 + (l>>4)*4 + jj), reduce over 16 column-lanes
    float m_[2][4], rs_[2][4];
    #pragma unroll
    for (int mt = 0; mt < 2; mt++) {
        #pragma unroll
        for (int jj = 0; jj < 4; jj++) {
            float s = 0.f, s2 = 0.f;
            #pragma unroll
            for (int nt = 0; nt < 7; nt++) {
                float v = acc2[mt][nt][jj];
                s += v;
                s2 = fmaf(v, v, s2);
            }
            #pragma unroll
            for (int msk = 1; msk < 16; msk <<= 1) {
                s  += __shfl_xor(s, msk);
                s2 += __shfl_xor(s2, msk);
            }
            float m = s * 0.01f;
            float var = fmaxf(s2 * 0.01f - m * m, 0.f);
            m_[mt][jj]  = m;
            rs_[mt][jj] = rsqrtf(var + 1e-5f);
        }
    }
    // column mean over rows<30: per-lane partial, then reduce over the 4 row-groups
    float cs[7];
    #pragma unroll
    for (int nt = 0; nt < 7; nt++) cs[nt] = 0.f;
    #pragma unroll
    for (int mt = 0; mt < 2; mt++) {
        #pragma unroll
        for (int jj = 0; jj < 4; jj++) {
            int row = mt * 16 + ((l >> 4) << 2) + jj;
            if (row < 30) {
                float m = m_[mt][jj], rs = rs_[mt][jj];
                #pragma unroll
                for (int nt = 0; nt < 7; nt++)
                    cs[nt] = fmaf(acc2[mt][nt][jj] - m, rs, cs[nt]);
            }
        }
    }
    #pragma unroll
    for (int nt = 0; nt < 7; nt++) {
        cs[nt] += __shfl_xor(cs[nt], 16);
        cs[nt] += __shfl_xor(cs[nt], 32);
    }
    if ((l >> 4) == 0) {
        #pragma unroll
        for (int nt = 0; nt < 7; nt++) {
            int col = nt * 16 + (l & 15);
            if (col < 100)
                stF[col] = ln_h_g[col] * cs[nt] * (1.0f / 30.0f) + ln_h_b[col];
        }
    }
    SB();
    // out projection: 100 outputs over 64 lanes
    #pragma unroll
    for (int p = 0; p < 2; p++) {
        int o = p * 64 + l;
        if (o < 100 && node < N) {
            float a = out_b[o];
            const float* wr = out_w + o * 100;
            #pragma unroll
            for (int c = 0; c < 100; c += 4) {
                float4 w4 = *(const float4*)(wr + c);
                f32x4 t4 = *(const f32x4*)&stF[c];
                a += w4.x * t4[0] + w4.y * t4[1] + w4.z * t4[2] + w4.w * t4[3];
            }
            out[(size_t)node * 100 + o] = a;
        }
    }
}

// ---------------------------------------------------------------- launch

extern "C" void kernel_launch(void* const* d_in, const int* in_sizes, int n_in,
                              void* d_out, int out_size, void* d_ws, size_t ws_size,
                              hipStream_t stream) {
    const float* edge_attr  = (const float*)d_in[0];
    const float* edge_time  = (const float*)d_in[1];
    const int*   node_batch = (const int*)d_in[2];
    const float* head_w = (const float*)d_in[4];
    const float* head_b = (const float*)d_in[5];
    const float* ln_t_g = (const float*)d_in[6];
    const float* ln_t_b = (const float*)d_in[7];
    const float* tok1_w = (const float*)d_in[8];
    const float* tok1_b = (const float*)d_in[9];
    const float* tok2_w = (const float*)d_in[10];
    const float* tok2_b = (const float*)d_in[11];
    const float* ln_c_g = (const float*)d_in[12];
    const float* ln_c_b = (const float*)d_in[13];
    const float* ch1_w  = (const float*)d_in[14];
    const float* ch1_b  = (const float*)d_in[15];
    const float* ch2_w  = (const float*)d_in[16];
    const float* ch2_b  = (const float*)d_in[17];
    const float* ln_h_g = (const float*)d_in[18];
    const float* ln_h_b = (const float*)d_in[19];
    const float* out_w  = (const float*)d_in[20];
    const float* out_b  = (const float*)d_in[21];
    float* out = (float*)d_out;

    const int E = in_sizes[2];
    const int N = out_size / HIDC;

    int* cnt     = (int*)d_ws;                            // N
    int* cursor  = cnt + N;                               // N
    int* offsets = cursor + N;                            // N
    int* order   = offsets + N;                           // E
    int* sel     = order + E;                             // N*K
    unsigned short* wf = (unsigned short*)(sel + (size_t)N * KTOK);  // 128000 ushort

    hipMemsetAsync(cnt, 0, (size_t)2 * N * sizeof(int), stream);
    count_kernel<<<(E + 255) / 256, 256, 0, stream>>>(node_batch, cnt, E);
    scan_kernel<<<1, SCAN_T, 0, stream>>>(cnt, offsets, N);
    fill_kernel<<<(E + 255) / 256, 256, 0, stream>>>(node_batch, cursor, offsets, order, E);
    select_kernel<<<(N + 255) / 256, 256, 0, stream>>>(cnt, offsets, order, sel, N);
    prep_kernel<<<500, 256, 0, stream>>>(head_w, ch1_w, ch2_w, tok1_w, tok2_w, wf);
    fused_node_kernel<<<(N + 1) / 2, 128, 0, stream>>>(
        edge_attr, edge_time, sel, wf, head_b,
        ln_t_g, ln_t_b, tok1_b, tok2_b, ln_c_g, ln_c_b,
        ch1_b, ch2_b, ln_h_g, ln_h_b, out_w, out_b, out, N);
}